// Round 12
// baseline (234.522 us; speedup 1.0000x reference)
//
#include <hip/hip_runtime.h>
#include <hip/hip_bf16.h>
#include <math.h>

// DscaGRUCell rev 12 — register-direct GEMM: NO LDS, NO barriers. Both
// operands are K-contiguous row-major (A, B^T), so each lane's MFMA fragment
// is a contiguous 16B global chunk -> load straight to VGPRs. Each wave is an
// independent 2-deep software pipeline; latency hidden by scoreboarding + TLP
// (no LDS => occupancy VGPR-bound only). T1 XCD swizzle keeps B/A L2-resident.

#define TAU_F 0.5f

typedef __bf16 bf16x8 __attribute__((ext_vector_type(8)));
typedef __bf16 bf16x4 __attribute__((ext_vector_type(4)));
typedef float f32x4 __attribute__((ext_vector_type(4)));

struct SubGemm {
    const void* A;    // M x lda (f32 if AFP32 else bf16)
    int lda;
    int Kvalid;       // AFP32: valid A cols (addr clamp; BT zero-padded beyond)
    const __bf16* BT; // N x Kpad row-major (pre-transposed, zero-padded bf16)
    int ldbt;
    float* C;         // out base (fp32 partials, or bf16 when obf16)
    int ldc;
    long long strideC;
    int Ksub;         // K per split slice (mult of 64 here; nt even)
    int nbx;          // col tiles (N/128)
    int pairSplit;    // ct >= this uses A + pairAOff
    int pairAOff;
    int obf16;
};

// 64x128 tile, 4 waves as 2x2 (each wave 32 rows x 64 cols = 2x4 frags of
// 16x16x32). Fragments loaded direct from global. 2-deep register pipeline.
template <bool AFP32>
__global__ __launch_bounds__(256) void gemm_dual(SubGemm g1, SubGemm g2, int blocks1)
{
    const int tid = threadIdx.x, w = tid >> 6, l = tid & 63;

    // T1 XCD-chunked swizzle (nwg % 8 == 0 for all launches here)
    const int gx = gridDim.x;
    const int nwg = gx * (int)gridDim.y;
    const int hw = (int)blockIdx.y * gx + (int)blockIdx.x;
    const int lg = (hw & 7) * (nwg >> 3) + (hw >> 3);
    const int bxl_lin = lg % gx;
    const int by = lg / gx;

    const bool second = bxl_lin >= blocks1;
    const SubGemm& g = second ? g2 : g1;
    const int bxl = second ? bxl_lin - blocks1 : bxl_lin;
    const int ct = bxl % g.nbx, spl = bxl / g.nbx;
    const int brow = by * 64, bcol = ct * 128;
    const int k_begin = spl * g.Ksub;
    const int nt = g.Ksub >> 5;               // even for all shapes used
    const int aoff = (ct >= g.pairSplit) ? g.pairAOff : 0;

    const int fr = l & 15, fk = (l >> 4) * 8;
    const int wr = (w >> 1) * 32, wc = (w & 1) * 64;

    // fragment row pointers (K-contiguous)
    const __bf16* b0 = g.BT + (size_t)(bcol + wc +  0 + fr) * g.ldbt + k_begin + fk;
    const __bf16* b1 = g.BT + (size_t)(bcol + wc + 16 + fr) * g.ldbt + k_begin + fk;
    const __bf16* b2 = g.BT + (size_t)(bcol + wc + 32 + fr) * g.ldbt + k_begin + fk;
    const __bf16* b3 = g.BT + (size_t)(bcol + wc + 48 + fr) * g.ldbt + k_begin + fk;

    const __bf16* a0b = (const __bf16*)g.A + aoff + (size_t)(brow + wr +  0 + fr) * g.lda + k_begin + fk;
    const __bf16* a1b = (const __bf16*)g.A + aoff + (size_t)(brow + wr + 16 + fr) * g.lda + k_begin + fk;
    const float*  a0f = (const float*)g.A + aoff + (size_t)(brow + wr +  0 + fr) * g.lda;
    const float*  a1f = (const float*)g.A + aoff + (size_t)(brow + wr + 16 + fr) * g.lda;
    const int kcl = g.Kvalid - 8;             // clamp; B zero-pad kills products

    struct FR { bf16x8 a0, a1, b0, b1, b2, b3; };

    auto ldA32 = [&](const float* rowp, int k) -> bf16x8 {
        int c = k_begin + k + fk;
        c = c < kcl ? c : kcl;
        f32x4 lo = *(const f32x4*)(rowp + c);
        f32x4 hi = *(const f32x4*)(rowp + c + 4);
        bf16x8 r;
#pragma unroll
        for (int z = 0; z < 4; ++z) { r[z] = (__bf16)lo[z]; r[4 + z] = (__bf16)hi[z]; }
        return r;
    };

    auto LD = [&](int k) -> FR {
        FR f;
        if constexpr (AFP32) {
            f.a0 = ldA32(a0f, k);
            f.a1 = ldA32(a1f, k);
        } else {
            f.a0 = *(const bf16x8*)(a0b + k);
            f.a1 = *(const bf16x8*)(a1b + k);
        }
        f.b0 = *(const bf16x8*)(b0 + k);
        f.b1 = *(const bf16x8*)(b1 + k);
        f.b2 = *(const bf16x8*)(b2 + k);
        f.b3 = *(const bf16x8*)(b3 + k);
        return f;
    };

    f32x4 acc[2][4] = {};
    auto MM = [&](const FR& f) {
        acc[0][0] = __builtin_amdgcn_mfma_f32_16x16x32_bf16(f.a0, f.b0, acc[0][0], 0, 0, 0);
        acc[0][1] = __builtin_amdgcn_mfma_f32_16x16x32_bf16(f.a0, f.b1, acc[0][1], 0, 0, 0);
        acc[0][2] = __builtin_amdgcn_mfma_f32_16x16x32_bf16(f.a0, f.b2, acc[0][2], 0, 0, 0);
        acc[0][3] = __builtin_amdgcn_mfma_f32_16x16x32_bf16(f.a0, f.b3, acc[0][3], 0, 0, 0);
        acc[1][0] = __builtin_amdgcn_mfma_f32_16x16x32_bf16(f.a1, f.b0, acc[1][0], 0, 0, 0);
        acc[1][1] = __builtin_amdgcn_mfma_f32_16x16x32_bf16(f.a1, f.b1, acc[1][1], 0, 0, 0);
        acc[1][2] = __builtin_amdgcn_mfma_f32_16x16x32_bf16(f.a1, f.b2, acc[1][2], 0, 0, 0);
        acc[1][3] = __builtin_amdgcn_mfma_f32_16x16x32_bf16(f.a1, f.b3, acc[1][3], 0, 0, 0);
    };

    // 2-deep register pipeline (static names; redundant tail loads harmless)
    FR f0 = LD(0);
    const int klast = (nt - 1) * 32;
    for (int t = 0; t < nt; t += 2) {
        FR f1 = LD((t + 1) * 32);
        MM(f0);
        int k2 = (t + 2) * 32;
        f0 = LD(k2 < klast ? k2 : klast);
        MM(f1);
    }

    // epilogue. C/D: col=lane&15, row=(lane>>4)*4+reg
    const int fq = (l >> 4) * 4;
    if (g.obf16) {
        __bf16* Cb = (__bf16*)g.C + (size_t)spl * g.strideC;
#pragma unroll
        for (int m = 0; m < 2; ++m)
#pragma unroll
            for (int n = 0; n < 4; ++n)
#pragma unroll
                for (int r = 0; r < 4; ++r) {
                    int row = brow + wr + m * 16 + fq + r;
                    int col = bcol + wc + n * 16 + fr;
                    Cb[(size_t)row * g.ldc + col] = (__bf16)acc[m][n][r];
                }
    } else {
        float* C = g.C + (size_t)spl * g.strideC;
#pragma unroll
        for (int m = 0; m < 2; ++m)
#pragma unroll
            for (int n = 0; n < 4; ++n)
#pragma unroll
                for (int r = 0; r < 4; ++r) {
                    int row = brow + wr + m * 16 + fq + r;
                    int col = bcol + wc + n * 16 + fr;
                    C[(size_t)row * g.ldc + col] = acc[m][n][r];
                }
    }
}

// ---------------- prep: LDS-tiled weight transposes --------------------------
__global__ __launch_bounds__(256) void prep_wT(
    const float* __restrict__ ew1, const float* __restrict__ ew2,
    const float* __restrict__ w12, const float* __restrict__ u12,
    const float* __restrict__ v12, const float* __restrict__ w21,
    const float* __restrict__ u21, const float* __restrict__ v21,
    const float* __restrict__ cd_w, const float* __restrict__ cw_w,
    const float* __restrict__ kern, const float* __restrict__ rkern,
    __bf16* __restrict__ WT, __bf16* __restrict__ WcatT,
    __bf16* __restrict__ cdT, __bf16* __restrict__ cwT,
    __bf16* __restrict__ kernT, __bf16* __restrict__ rkernT)
{
    __shared__ float tile[64][65];
    const int b = blockIdx.x, tid = threadIdx.x;
    const int tr = tid >> 6, tc = tid & 63;

    const float* src = nullptr;
    int ldsrc = 0, srow0 = 0, scol0 = 0, kvalid = 1 << 30;
    __bf16* dst; int ldd, n0, k0;
    bool zero = false;

    if (b < 256) {                         // WT: out 512 x 2048
        int q = b; n0 = (q >> 5) * 64; k0 = (q & 31) * 64;
        dst = WT; ldd = 2048; kvalid = 2000; ldsrc = 256; srow0 = k0;
        if (n0 < 256) { src = ew1; scol0 = n0; } else { src = ew2; scol0 = n0 - 256; }
    } else if (b < 384) {                  // WcatT: out 1024 x 512
        int q = b - 256; n0 = (q >> 3) * 64; k0 = (q & 7) * 64;
        dst = WcatT; ldd = 512; ldsrc = 256; srow0 = k0 & 255; scol0 = n0 & 255;
        int qn = n0 >> 8; bool khi = k0 >= 256;
        if (qn == 0)      src = khi ? u12 : w12;
        else if (qn == 1) src = khi ? w21 : u21;
        else if (qn == 2) { if (khi) src = v12; else zero = true; }
        else              { if (khi) zero = true; else src = v21; }
    } else if (b < 448) {                  // cdT
        int q = b - 384; n0 = (q >> 3) * 64; k0 = (q & 7) * 64;
        src = cd_w; ldsrc = 512; srow0 = k0; scol0 = n0; dst = cdT; ldd = 512;
    } else if (b < 512) {                  // cwT
        int q = b - 448; n0 = (q >> 3) * 64; k0 = (q & 7) * 64;
        src = cw_w; ldsrc = 512; srow0 = k0; scol0 = n0; dst = cwT; ldd = 512;
    } else if (b < 704) {                  // kernT
        int q = b - 512; n0 = (q >> 3) * 64; k0 = (q & 7) * 64;
        src = kern; ldsrc = 1536; srow0 = k0; scol0 = n0; dst = kernT; ldd = 512;
    } else {                               // rkernT
        int q = b - 704; n0 = (q >> 3) * 64; k0 = (q & 7) * 64;
        src = rkern; ldsrc = 1536; srow0 = k0; scol0 = n0; dst = rkernT; ldd = 512;
    }

#pragma unroll
    for (int p = 0; p < 16; ++p) {
        int kr = p * 4 + tr;
        float v = 0.f;
        if (!zero && (srow0 + kr) < kvalid)
            v = src[(size_t)(srow0 + kr) * ldsrc + scol0 + tc];
        tile[kr][tc] = v;
    }
    __syncthreads();
#pragma unroll
    for (int p = 0; p < 16; ++p) {
        int nr = p * 4 + tr;
        dst[(size_t)(n0 + nr) * ldd + k0 + tc] = (__bf16)tile[tc][nr];
    }
}

// ---------------- R-A: E = bf16(sum2 P12), cro = bf16(tanh(P4 + cd_b)) ------
__global__ __launch_bounds__(256) void reduce_A(
    const float* __restrict__ P12, const float* __restrict__ P4,
    const float* __restrict__ cd_b,
    __bf16* __restrict__ E, __bf16* __restrict__ cro)
{
    const int S = 1 << 21;
    int b = blockIdx.x;
    int i = (((b & 2047) * 256) + threadIdx.x) * 4;
    if (b < 2048) {
        f32x4 p0 = *(const f32x4*)(P12 + i);
        f32x4 p1 = *(const f32x4*)(P12 + S + i);
        __bf16 o[4];
#pragma unroll
        for (int j = 0; j < 4; ++j) o[j] = (__bf16)(p0[j] + p1[j]);
        *(bf16x4*)&E[i] = *(bf16x4*)o;
    } else {
        f32x4 p0 = *(const f32x4*)(P4 + i);
        int c = i & 511;
        __bf16 o[4];
#pragma unroll
        for (int j = 0; j < 4; ++j) o[j] = (__bf16)tanhf(p0[j] + cd_b[c + j]);
        *(bf16x4*)&cro[i] = *(bf16x4*)o;
    }
}

// ---------------- fuse1: attention + x + crohis_new, and hprev ---------------
__global__ __launch_bounds__(256) void fuse1(
    const __bf16* __restrict__ T, const __bf16* __restrict__ E,
    const float* __restrict__ crohis,
    const float* __restrict__ P5,
    const float* __restrict__ h_tm1, const float* __restrict__ cw_b,
    __bf16* __restrict__ x, float* __restrict__ cro_out,
    float* __restrict__ hprev, __bf16* __restrict__ hprev_bf)
{
    __shared__ float s4[4];
    int b = blockIdx.x;
    int j = threadIdx.x;
    if (b < 4096) {
        const __bf16* t = T + (size_t)b * 1024;
        float s12 = tanhf((float)t[j])       * (float)t[512 + j];
        float s21 = tanhf((float)t[256 + j]) * (float)t[768 + j];
        float v = s12;
#pragma unroll
        for (int o = 32; o >= 1; o >>= 1) v = fmaxf(v, __shfl_xor(v, o, 64));
        __syncthreads(); if ((j & 63) == 0) s4[j >> 6] = v; __syncthreads();
        float m12 = fmaxf(fmaxf(s4[0], s4[1]), fmaxf(s4[2], s4[3]));
        float e12 = expf(s12 - m12);
        v = e12;
#pragma unroll
        for (int o = 32; o >= 1; o >>= 1) v += __shfl_xor(v, o, 64);
        __syncthreads(); if ((j & 63) == 0) s4[j >> 6] = v; __syncthreads();
        float sum12 = s4[0] + s4[1] + s4[2] + s4[3];
        v = s21;
#pragma unroll
        for (int o = 32; o >= 1; o >>= 1) v = fmaxf(v, __shfl_xor(v, o, 64));
        __syncthreads(); if ((j & 63) == 0) s4[j >> 6] = v; __syncthreads();
        float m21 = fmaxf(fmaxf(s4[0], s4[1]), fmaxf(s4[2], s4[3]));
        float e21 = expf(s21 - m21);
        v = e21;
#pragma unroll
        for (int o = 32; o >= 1; o >>= 1) v += __shfl_xor(v, o, 64);
        __syncthreads(); if ((j & 63) == 0) s4[j >> 6] = v; __syncthreads();
        float sum21 = s4[0] + s4[1] + s4[2] + s4[3];

        size_t b0 = (size_t)b * 512 + j, b1 = b0 + 256;
        float x1 = (float)E[b0] * (e12 / sum12);
        float x2 = (float)E[b1] * (e21 / sum21);
        x[b0] = (__bf16)x1;
        x[b1] = (__bf16)x2;
        cro_out[b0] = TAU_F * crohis[b0] + (1.f - TAU_F) * x1;
        cro_out[b1] = TAU_F * crohis[b1] + (1.f - TAU_F) * x2;
    } else {
        int i = ((b - 4096) * 256 + j) * 4;
        f32x4 p = *(const f32x4*)(P5 + i);
        f32x4 ht = *(const f32x4*)(h_tm1 + i);
        int c = i & 511;
        f32x4 o; __bf16 ob[4];
#pragma unroll
        for (int q = 0; q < 4; ++q) {
            float hv = ht[q] + tanhf(p[q] + cw_b[c + q]);
            o[q] = hv; ob[q] = (__bf16)hv;
        }
        *(f32x4*)(hprev + i) = o;
        *(bf16x4*)&hprev_bf[i] = *(bf16x4*)ob;
    }
}

// ---------------- gates: rh = sigmoid(mx_r + bias_r + mi_r) * hprev ----------
__global__ __launch_bounds__(256) void gates_k(
    const float* __restrict__ mx, const float* __restrict__ mi2,
    const float* __restrict__ hprev, const float* __restrict__ bias,
    __bf16* __restrict__ rh)
{
    int i = (blockIdx.x * 256 + threadIdx.x) * 4;
    int row = i >> 9, c = i & 511;
    f32x4 a  = *(const f32x4*)(mx + (size_t)row * 1536 + 512 + c);
    f32x4 m  = *(const f32x4*)(mi2 + (size_t)row * 1024 + 512 + c);
    f32x4 hp = *(const f32x4*)(hprev + i);
    f32x4 bb = *(const f32x4*)(bias + 512 + c);
    __bf16 o[4];
#pragma unroll
    for (int q = 0; q < 4; ++q) {
        float r = 1.f / (1.f + expf(-(a[q] + bb[q] + m[q])));
        o[q] = (__bf16)(r * hp[q]);
    }
    *(bf16x4*)&rh[i] = *(bf16x4*)o;
}

// ---------------- final: h ---------------------------------------------------
__global__ __launch_bounds__(256) void final_k(
    const float* __restrict__ mx, const float* __restrict__ mi2,
    const float* __restrict__ P8a, const float* __restrict__ P8b,
    const float* __restrict__ hprev, const float* __restrict__ bias,
    float* __restrict__ h)
{
    int i = (blockIdx.x * 256 + threadIdx.x) * 4;
    int row = i >> 9, c = i & 511;
    f32x4 xz = *(const f32x4*)(mx + (size_t)row * 1536 + c);
    f32x4 xh = *(const f32x4*)(mx + (size_t)row * 1536 + 1024 + c);
    f32x4 mz = *(const f32x4*)(mi2 + (size_t)row * 1024 + c);
    f32x4 p0 = *(const f32x4*)(P8a + i);
    f32x4 p1 = *(const f32x4*)(P8b + i);
    f32x4 hp = *(const f32x4*)(hprev + i);
    f32x4 bz = *(const f32x4*)(bias + c);
    f32x4 bh = *(const f32x4*)(bias + 1024 + c);
    f32x4 o;
#pragma unroll
    for (int q = 0; q < 4; ++q) {
        float z = 1.f / (1.f + expf(-(xz[q] + bz[q] + mz[q])));
        float hh = tanhf(xh[q] + bh[q] + p0[q] + p1[q]);
        o[q] = z * hp[q] + (1.f - z) * hh;
    }
    *(f32x4*)(h + i) = o;
}

// ---------------- launch -----------------------------------------------------
extern "C" void kernel_launch(void* const* d_in, const int* in_sizes, int n_in,
                              void* d_out, int out_size, void* d_ws, size_t ws_size,
                              hipStream_t stream)
{
    (void)in_sizes; (void)n_in; (void)out_size; (void)ws_size;

    const float* inputs = (const float*)d_in[0];
    const float* h_tm1  = (const float*)d_in[1];
    const float* crohis = (const float*)d_in[2];
    const float* ew1    = (const float*)d_in[3];
    const float* ew2    = (const float*)d_in[4];
    const float* ca12w  = (const float*)d_in[5];
    const float* ca12u  = (const float*)d_in[6];
    const float* ca12v  = (const float*)d_in[7];
    const float* ca21w  = (const float*)d_in[8];
    const float* ca21u  = (const float*)d_in[9];
    const float* ca21v  = (const float*)d_in[10];
    const float* cw_w   = (const float*)d_in[11];
    const float* cw_b   = (const float*)d_in[12];
    const float* cd_w   = (const float*)d_in[13];
    const float* cd_b   = (const float*)d_in[14];
    const float* kern   = (const float*)d_in[15];
    const float* rkern  = (const float*)d_in[16];
    const float* bias   = (const float*)d_in[17];

    char* ws = (char*)d_ws;
    const size_t MB = 1 << 20;
    // layout (lifetimes verified disjoint):
    //  0-16  P12 x2 [A] -> P5 @0-8 [B..fuse1] -> mi2 @0-16 [C..final]
    // 16-20  x [fuse1..C] -> rh [gates..G8]
    // 20-28  hprev [fuse1..final]
    // 28-32  hprev_bf [fuse1..C]
    // 32-40  P4 [A] -> mx @32-56 [C..final]
    // 48-52  E [redA..fuse1]   (dead before C writes mx over it)
    // 52-56  cro_bf [redA..B]
    // 56-64  T bf16 [B..fuse1] -> P8 s0 [G8..final]
    // 64-72  P8 s1
    // 72-79  weights
    float*  P12      = (float*)(ws + 0);
    float*  P5       = (float*)(ws + 0);
    float*  mi2      = (float*)(ws + 0);
    __bf16* x        = (__bf16*)(ws + 16 * MB);
    __bf16* rh       = (__bf16*)(ws + 16 * MB);
    float*  hprev    = (float*)(ws + 20 * MB);
    __bf16* hprev_bf = (__bf16*)(ws + 28 * MB);
    float*  P4       = (float*)(ws + 32 * MB);
    float*  mx       = (float*)(ws + 32 * MB);
    __bf16* E        = (__bf16*)(ws + 48 * MB);
    __bf16* cro_bf   = (__bf16*)(ws + 52 * MB);
    __bf16* T        = (__bf16*)(ws + 56 * MB);
    float*  P8       = (float*)(ws + 56 * MB);
    __bf16* WT       = (__bf16*)(ws + 72 * MB);               // 2MB
    __bf16* WcatT    = (__bf16*)(ws + 74 * MB);               // 1MB
    __bf16* cdT      = (__bf16*)(ws + 75 * MB);               // 0.5MB
    __bf16* cwT      = (__bf16*)(ws + 75 * MB + 512 * 1024);  // 0.5MB
    __bf16* kernT    = (__bf16*)(ws + 76 * MB);               // 1.5MB
    __bf16* rkernT   = (__bf16*)(ws + 77 * MB + 512 * 1024);  // ends 79MB

    float* h_out   = (float*)d_out;
    float* cro_out = (float*)d_out + 2 * 1048576;

    const int BIG = 1 << 30;
    const long long S2 = 1ll << 21;   // 8MB slice stride (fp32 elems)

    prep_wT<<<896, 256, 0, stream>>>(ew1, ew2, ca12w, ca12u, ca12v, ca21w,
                                     ca21u, ca21v, cd_w, cw_w, kern, rkern,
                                     WT, WcatT, cdT, cwT, kernT, rkernT);

    // Phase A: G12 split-2 (fp32 inputs) + G4 (fp32 crohis)   [grid (12,64)=768]
    SubGemm gA1 = { inputs, 4000, 2000, WT,  2048, P12, 512, S2, 1024, 4, 2, 2000, 0 };
    SubGemm gA2 = { crohis,  512,  512, cdT,  512, P4,  512, 0,   512, 4, BIG, 0, 0 };
    gemm_dual<true><<<dim3(12, 64), 256, 0, stream>>>(gA1, gA2, 8);

    reduce_A<<<4096, 256, 0, stream>>>(P12, P4, cd_b, E, cro_bf);

    // Phase B: G3 (bf16 T out) + G5                            [grid (12,64)=768]
    SubGemm gB1 = { E,      512, 512, WcatT, 512, (float*)T, 1024, 0, 512, 8, BIG, 0, 1 };
    SubGemm gB2 = { cro_bf, 512, 512, cwT,   512, P5,        512,  0, 512, 4, BIG, 0, 0 };
    gemm_dual<false><<<dim3(12, 64), 256, 0, stream>>>(gB1, gB2, 8);

    fuse1<<<6144, 256, 0, stream>>>(T, E, crohis, P5, h_tm1, cw_b,
                                    x, cro_out, hprev, hprev_bf);

    // Phase C: G6 (mx) + G7 (mi2)                               [grid (20,64)=1280]
    SubGemm gC1 = { x,        512, 512, kernT,  512, mx,  1536, 0, 512, 12, BIG, 0, 0 };
    SubGemm gC2 = { hprev_bf, 512, 512, rkernT, 512, mi2, 1024, 0, 512, 8,  BIG, 0, 0 };
    gemm_dual<false><<<dim3(20, 64), 256, 0, stream>>>(gC1, gC2, 12);

    gates_k<<<2048, 256, 0, stream>>>(mx, mi2, hprev, bias, rh);

    // G8: split-2                                               [grid (8,64)=512]
    SubGemm gG = { rh, 512, 512, rkernT + (size_t)1024 * 512, 512, P8, 512, S2, 256, 4, BIG, 0, 0 };
    gemm_dual<false><<<dim3(8, 64), 256, 0, stream>>>(gG, gG, 8);

    final_k<<<2048, 256, 0, stream>>>(mx, mi2, P8, P8 + S2, hprev, bias, h_out);
}

// Round 13
// 175.010 us; speedup vs baseline: 1.3401x; 1.3401x over previous
//
#include <hip/hip_runtime.h>
#include <hip/hip_bf16.h>
#include <math.h>

// DscaGRUCell rev 13 — rev 10's proven GEMM pipelines (bf16 depth-3 vmcnt(6);
// fp32-A via gload_lds fp32-LDS depth-2 vmcnt(4)) + fused runtime epilogues:
// no split-K, no reduce/final kernels, bf16 intermediates everywhere except
// hprev/cro_out/h. Flat workspace (no aliasing). T1 XCD swizzle retained.

#define TAU_F 0.5f

typedef __bf16 bf16x8 __attribute__((ext_vector_type(8)));
typedef __bf16 bf16x4 __attribute__((ext_vector_type(4)));
typedef float f32x4 __attribute__((ext_vector_type(4)));

__device__ __forceinline__ void gload16(const void* g, void* l) {
    __builtin_amdgcn_global_load_lds(
        (const __attribute__((address_space(1))) void*)g,
        (__attribute__((address_space(3))) void*)l, 16, 0, 0);
}

// epilogue modes:
// 0: C f32 = acc
// 1: Cb bf16 = acc
// 2: Cb bf16 = acc + bias[col]
// 3: Cb bf16 = tanh(acc + bias[col])
// 4: hv = base[row,col] + tanh(acc + bias[col]); C f32 = hv; Cb = bf16(hv)  (N=512)
// 5: GRU final: z=sig(mx_z+mi_z); hh=tanh(mx_h+acc); C f32 = z*base+(1-z)*hh (N=512)
struct SubGemm {
    const void* A;    // M x lda (f32 if AFP32 else bf16)
    int lda;
    int Kvalid;       // AFP32: valid A cols (addr clamp; BT zero-padded beyond)
    const __bf16* BT; // N x Kpad row-major (pre-transposed, zero-padded bf16)
    int ldbt;
    float* C;
    __bf16* Cb;
    int ldc;
    int Ksub;         // full K (mult of 32)
    int nbx;          // col tiles (N/128)
    int pairSplit;    // ct >= this uses A + pairAOff
    int pairAOff;
    int mode;
    const float* bias;
    const float* base;      // h_tm1 (mode4) / hprev f32 (mode5)
    const __bf16* mxp;      // mode5: mx_bf (ld 1536, bias pre-added)
    const __bf16* mip;      // mode5: mi2_bf (ld 1024)
};

// 64x128 tile, BK=32, 4 waves (2x4 frags of 16x16x32 bf16 MFMA).
template <bool AFP32>
__global__ __launch_bounds__(256) void gemm_dual(SubGemm g1, SubGemm g2, int blocks1)
{
    __shared__ __attribute__((aligned(16))) char lds[49152];

    const int tid = threadIdx.x, w = tid >> 6, l = tid & 63;

    // T1 XCD-chunked swizzle (nwg % 8 == 0 for all launches here)
    const int gx = gridDim.x;
    const int nwg = gx * (int)gridDim.y;
    const int hw = (int)blockIdx.y * gx + (int)blockIdx.x;
    const int lg = (hw & 7) * (nwg >> 3) + (hw >> 3);
    const int bxl_lin = lg % gx;
    const int by = lg / gx;

    const bool second = bxl_lin >= blocks1;
    const SubGemm& g = second ? g2 : g1;
    const int ct = second ? bxl_lin - blocks1 : bxl_lin;
    const int brow = by * 64, bcol = ct * 128;
    const int nt = g.Ksub >> 5;
    const int aoff = (ct >= g.pairSplit) ? g.pairAOff : 0;

    const int sbr = w * 32 + (l >> 2);        // B staging rows (2 issues)
    const int seg = (l & 3) * 8;

    const __bf16* Bg0 = g.BT + (size_t)(bcol + sbr) * g.ldbt + seg;
    const __bf16* Bg1 = Bg0 + (size_t)16 * g.ldbt;

    f32x4 acc[2][4] = {};
    const int fr = l & 15, fk = (l >> 4) * 8;
    const int wr = (w >> 1) * 32, wc = (w & 1) * 64;
    const int kmax = (nt - 1) * 32;

    if constexpr (AFP32) {
        // LDS: Af32 3 x [64][32] f32 (24KB) | Bs 3 x [128][32] bf16 (24KB)
        auto Af32 = (float (*)[64][32])lds;
        auto Bs   = (__bf16 (*)[128][32])(lds + 24576);

        const float* ArowBase = (const float*)g.A + aoff
                              + (size_t)(brow + w * 16 + (l >> 3)) * g.lda;
        const int colLane = (l & 7) * 4;
        const int kcl4 = g.Kvalid - 4;

#define ISSUE_A32(slot)                                                       \
        {                                                                     \
            const int _s = (slot);                                            \
            const int _k = (_s * 32 < kmax) ? _s * 32 : kmax;                 \
            const int _b = _s % 3;                                            \
            int c0 = _k + colLane;                                            \
            c0 = c0 < kcl4 ? c0 : kcl4;                                       \
            gload16(ArowBase + c0,             &Af32[_b][w * 16][0]);         \
            gload16(ArowBase + 8 * g.lda + c0, &Af32[_b][w * 16 + 8][0]);     \
            gload16(Bg0 + _k, &Bs[_b][w * 32][0]);                            \
            gload16(Bg1 + _k, &Bs[_b][w * 32 + 16][0]);                       \
        }

        ISSUE_A32(0) ISSUE_A32(1)

        for (int t = 0; t < nt; ++t) {
            asm volatile("s_waitcnt vmcnt(4)" ::: "memory");
            asm volatile("s_waitcnt lgkmcnt(0)" ::: "memory");
            __builtin_amdgcn_s_barrier();

            const int bi = t % 3;
            bf16x8 a[2]; bf16x8 b[4];
#pragma unroll
            for (int m = 0; m < 2; ++m) {
                f32x4 lo = *(const f32x4*)&Af32[bi][wr + m * 16 + fr][fk];
                f32x4 hi = *(const f32x4*)&Af32[bi][wr + m * 16 + fr][fk + 4];
#pragma unroll
                for (int z = 0; z < 4; ++z) { a[m][z] = (__bf16)lo[z]; a[m][4 + z] = (__bf16)hi[z]; }
            }
#pragma unroll
            for (int n = 0; n < 4; ++n) b[n] = *(const bf16x8*)&Bs[bi][wc + n * 16 + fr][fk];

            ISSUE_A32(t + 2)

#pragma unroll
            for (int m = 0; m < 2; ++m)
#pragma unroll
                for (int n = 0; n < 4; ++n)
                    acc[m][n] = __builtin_amdgcn_mfma_f32_16x16x32_bf16(a[m], b[n], acc[m][n], 0, 0, 0);
        }
#undef ISSUE_A32
    } else {
        // LDS: As 4 x [64][32] bf16 (16KB) | Bs 4 x [128][32] bf16 (32KB)
        auto As = (__bf16 (*)[64][32])lds;
        auto Bs = (__bf16 (*)[128][32])(lds + 16384);

        const int sar = w * 16 + (l >> 2);
        const __bf16* Ar = (const __bf16*)g.A + aoff
                         + (size_t)(brow + sar) * g.lda + seg;

#define ISSUE_AB(slot)                                                        \
        {                                                                     \
            const int _s = (slot);                                            \
            const int _k = (_s * 32 < kmax) ? _s * 32 : kmax;                 \
            const int _b = _s & 3;                                            \
            gload16(Ar + _k,  &As[_b][w * 16][0]);                            \
            gload16(Bg0 + _k, &Bs[_b][w * 32][0]);                            \
            gload16(Bg1 + _k, &Bs[_b][w * 32 + 16][0]);                       \
        }

        ISSUE_AB(0) ISSUE_AB(1) ISSUE_AB(2)

        for (int t = 0; t < nt; ++t) {
            asm volatile("s_waitcnt vmcnt(6)" ::: "memory");
            asm volatile("s_waitcnt lgkmcnt(0)" ::: "memory");
            __builtin_amdgcn_s_barrier();

            const int bi = t & 3;
            bf16x8 a[2], b[4];
#pragma unroll
            for (int m = 0; m < 2; ++m) a[m] = *(const bf16x8*)&As[bi][wr + m * 16 + fr][fk];
#pragma unroll
            for (int n = 0; n < 4; ++n) b[n] = *(const bf16x8*)&Bs[bi][wc + n * 16 + fr][fk];

            ISSUE_AB(t + 3)

#pragma unroll
            for (int m = 0; m < 2; ++m)
#pragma unroll
                for (int n = 0; n < 4; ++n)
                    acc[m][n] = __builtin_amdgcn_mfma_f32_16x16x32_bf16(a[m], b[n], acc[m][n], 0, 0, 0);
        }
#undef ISSUE_AB
    }

    // fused epilogue. C/D: col=lane&15, row=(lane>>4)*4+reg
    const int fq = (l >> 4) * 4;
    const int mode = g.mode;
#pragma unroll
    for (int m = 0; m < 2; ++m)
#pragma unroll
        for (int n = 0; n < 4; ++n)
#pragma unroll
            for (int r = 0; r < 4; ++r) {
                int row = brow + wr + m * 16 + fq + r;
                int col = bcol + wc + n * 16 + fr;
                float v = acc[m][n][r];
                if (mode == 0) {
                    g.C[(size_t)row * g.ldc + col] = v;
                } else if (mode == 1) {
                    g.Cb[(size_t)row * g.ldc + col] = (__bf16)v;
                } else if (mode == 2) {
                    g.Cb[(size_t)row * g.ldc + col] = (__bf16)(v + g.bias[col]);
                } else if (mode == 3) {
                    g.Cb[(size_t)row * g.ldc + col] = (__bf16)tanhf(v + g.bias[col]);
                } else if (mode == 4) {
                    float hv = g.base[(size_t)row * 512 + col] + tanhf(v + g.bias[col]);
                    g.C[(size_t)row * 512 + col] = hv;
                    g.Cb[(size_t)row * 512 + col] = (__bf16)hv;
                } else {   // 5: GRU final (mx/mi bias pre-added)
                    float xz = (float)g.mxp[(size_t)row * 1536 + col];
                    float xh = (float)g.mxp[(size_t)row * 1536 + 1024 + col];
                    float mz = (float)g.mip[(size_t)row * 1024 + col];
                    float hp = g.base[(size_t)row * 512 + col];
                    float z  = 1.f / (1.f + expf(-(xz + mz)));
                    float hh = tanhf(xh + v);
                    g.C[(size_t)row * 512 + col] = z * hp + (1.f - z) * hh;
                }
            }
}

// ---------------- prep: LDS-tiled weight transposes --------------------------
__global__ __launch_bounds__(256) void prep_wT(
    const float* __restrict__ ew1, const float* __restrict__ ew2,
    const float* __restrict__ w12, const float* __restrict__ u12,
    const float* __restrict__ v12, const float* __restrict__ w21,
    const float* __restrict__ u21, const float* __restrict__ v21,
    const float* __restrict__ cd_w, const float* __restrict__ cw_w,
    const float* __restrict__ kern, const float* __restrict__ rkern,
    __bf16* __restrict__ WT, __bf16* __restrict__ WcatT,
    __bf16* __restrict__ cdT, __bf16* __restrict__ cwT,
    __bf16* __restrict__ kernT, __bf16* __restrict__ rkernT)
{
    __shared__ float tile[64][65];
    const int b = blockIdx.x, tid = threadIdx.x;
    const int tr = tid >> 6, tc = tid & 63;

    const float* src = nullptr;
    int ldsrc = 0, srow0 = 0, scol0 = 0, kvalid = 1 << 30;
    __bf16* dst; int ldd, n0, k0;
    bool zero = false;

    if (b < 256) {                         // WT: out 512 x 2048
        int q = b; n0 = (q >> 5) * 64; k0 = (q & 31) * 64;
        dst = WT; ldd = 2048; kvalid = 2000; ldsrc = 256; srow0 = k0;
        if (n0 < 256) { src = ew1; scol0 = n0; } else { src = ew2; scol0 = n0 - 256; }
    } else if (b < 384) {                  // WcatT: out 1024 x 512
        int q = b - 256; n0 = (q >> 3) * 64; k0 = (q & 7) * 64;
        dst = WcatT; ldd = 512; ldsrc = 256; srow0 = k0 & 255; scol0 = n0 & 255;
        int qn = n0 >> 8; bool khi = k0 >= 256;
        if (qn == 0)      src = khi ? u12 : w12;
        else if (qn == 1) src = khi ? w21 : u21;
        else if (qn == 2) { if (khi) src = v12; else zero = true; }
        else              { if (khi) zero = true; else src = v21; }
    } else if (b < 448) {                  // cdT
        int q = b - 384; n0 = (q >> 3) * 64; k0 = (q & 7) * 64;
        src = cd_w; ldsrc = 512; srow0 = k0; scol0 = n0; dst = cdT; ldd = 512;
    } else if (b < 512) {                  // cwT
        int q = b - 448; n0 = (q >> 3) * 64; k0 = (q & 7) * 64;
        src = cw_w; ldsrc = 512; srow0 = k0; scol0 = n0; dst = cwT; ldd = 512;
    } else if (b < 704) {                  // kernT
        int q = b - 512; n0 = (q >> 3) * 64; k0 = (q & 7) * 64;
        src = kern; ldsrc = 1536; srow0 = k0; scol0 = n0; dst = kernT; ldd = 512;
    } else {                               // rkernT
        int q = b - 704; n0 = (q >> 3) * 64; k0 = (q & 7) * 64;
        src = rkern; ldsrc = 1536; srow0 = k0; scol0 = n0; dst = rkernT; ldd = 512;
    }

#pragma unroll
    for (int p = 0; p < 16; ++p) {
        int kr = p * 4 + tr;
        float v = 0.f;
        if (!zero && (srow0 + kr) < kvalid)
            v = src[(size_t)(srow0 + kr) * ldsrc + scol0 + tc];
        tile[kr][tc] = v;
    }
    __syncthreads();
#pragma unroll
    for (int p = 0; p < 16; ++p) {
        int nr = p * 4 + tr;
        dst[(size_t)(n0 + nr) * ldd + k0 + tc] = (__bf16)tile[tc][nr];
    }
}

// ---------------- attention: softmax + x + crohis_new ------------------------
__global__ __launch_bounds__(256) void fuse_att(
    const __bf16* __restrict__ T, const __bf16* __restrict__ E,
    const float* __restrict__ crohis,
    __bf16* __restrict__ x, float* __restrict__ cro_out)
{
    __shared__ float s4[4];
    int b = blockIdx.x;
    int j = threadIdx.x;
    const __bf16* t = T + (size_t)b * 1024;
    float s12 = tanhf((float)t[j])       * (float)t[512 + j];
    float s21 = tanhf((float)t[256 + j]) * (float)t[768 + j];
    float v = s12;
#pragma unroll
    for (int o = 32; o >= 1; o >>= 1) v = fmaxf(v, __shfl_xor(v, o, 64));
    __syncthreads(); if ((j & 63) == 0) s4[j >> 6] = v; __syncthreads();
    float m12 = fmaxf(fmaxf(s4[0], s4[1]), fmaxf(s4[2], s4[3]));
    float e12 = expf(s12 - m12);
    v = e12;
#pragma unroll
    for (int o = 32; o >= 1; o >>= 1) v += __shfl_xor(v, o, 64);
    __syncthreads(); if ((j & 63) == 0) s4[j >> 6] = v; __syncthreads();
    float sum12 = s4[0] + s4[1] + s4[2] + s4[3];
    v = s21;
#pragma unroll
    for (int o = 32; o >= 1; o >>= 1) v = fmaxf(v, __shfl_xor(v, o, 64));
    __syncthreads(); if ((j & 63) == 0) s4[j >> 6] = v; __syncthreads();
    float m21 = fmaxf(fmaxf(s4[0], s4[1]), fmaxf(s4[2], s4[3]));
    float e21 = expf(s21 - m21);
    v = e21;
#pragma unroll
    for (int o = 32; o >= 1; o >>= 1) v += __shfl_xor(v, o, 64);
    __syncthreads(); if ((j & 63) == 0) s4[j >> 6] = v; __syncthreads();
    float sum21 = s4[0] + s4[1] + s4[2] + s4[3];

    size_t b0 = (size_t)b * 512 + j, b1 = b0 + 256;
    float x1 = (float)E[b0] * (e12 / sum12);
    float x2 = (float)E[b1] * (e21 / sum21);
    x[b0] = (__bf16)x1;
    x[b1] = (__bf16)x2;
    cro_out[b0] = TAU_F * crohis[b0] + (1.f - TAU_F) * x1;
    cro_out[b1] = TAU_F * crohis[b1] + (1.f - TAU_F) * x2;
}

// ---------------- gates: rh = sigmoid(mx_r + mi_r) * hprev (all bf16) --------
__global__ __launch_bounds__(256) void gates_k(
    const __bf16* __restrict__ mx, const __bf16* __restrict__ mi,
    const __bf16* __restrict__ hprev_bf, __bf16* __restrict__ rh)
{
    int i = (blockIdx.x * 256 + threadIdx.x) * 4;
    int row = i >> 9, c = i & 511;
    bf16x4 a  = *(const bf16x4*)(mx + (size_t)row * 1536 + 512 + c);
    bf16x4 m  = *(const bf16x4*)(mi + (size_t)row * 1024 + 512 + c);
    bf16x4 hp = *(const bf16x4*)(hprev_bf + i);
    __bf16 o[4];
#pragma unroll
    for (int q = 0; q < 4; ++q) {
        float r = 1.f / (1.f + expf(-((float)a[q] + (float)m[q])));
        o[q] = (__bf16)(r * (float)hp[q]);
    }
    *(bf16x4*)&rh[i] = *(bf16x4*)o;
}

// ---------------- launch -----------------------------------------------------
extern "C" void kernel_launch(void* const* d_in, const int* in_sizes, int n_in,
                              void* d_out, int out_size, void* d_ws, size_t ws_size,
                              hipStream_t stream)
{
    (void)in_sizes; (void)n_in; (void)out_size; (void)ws_size;

    const float* inputs = (const float*)d_in[0];
    const float* h_tm1  = (const float*)d_in[1];
    const float* crohis = (const float*)d_in[2];
    const float* ew1    = (const float*)d_in[3];
    const float* ew2    = (const float*)d_in[4];
    const float* ca12w  = (const float*)d_in[5];
    const float* ca12u  = (const float*)d_in[6];
    const float* ca12v  = (const float*)d_in[7];
    const float* ca21w  = (const float*)d_in[8];
    const float* ca21u  = (const float*)d_in[9];
    const float* ca21v  = (const float*)d_in[10];
    const float* cw_w   = (const float*)d_in[11];
    const float* cw_b   = (const float*)d_in[12];
    const float* cd_w   = (const float*)d_in[13];
    const float* cd_b   = (const float*)d_in[14];
    const float* kern   = (const float*)d_in[15];
    const float* rkern  = (const float*)d_in[16];
    const float* bias   = (const float*)d_in[17];

    char* ws = (char*)d_ws;
    const size_t MB = 1 << 20;
    // FLAT layout — every buffer disjoint for the whole call (71 MB total):
    __bf16* E        = (__bf16*)(ws + 0);          // 4MB  4096x512
    __bf16* cro_bf   = (__bf16*)(ws + 4 * MB);     // 4MB
    __bf16* T        = (__bf16*)(ws + 8 * MB);     // 8MB  4096x1024
    __bf16* x        = (__bf16*)(ws + 16 * MB);    // 4MB
    float*  hprev    = (float*)(ws + 20 * MB);     // 16MB fp32
    __bf16* hprev_bf = (__bf16*)(ws + 36 * MB);    // 4MB
    __bf16* mx_bf    = (__bf16*)(ws + 40 * MB);    // 12MB 4096x1536 (bias added)
    __bf16* mi2_bf   = (__bf16*)(ws + 52 * MB);    // 8MB  4096x1024
    __bf16* rh       = (__bf16*)(ws + 60 * MB);    // 4MB
    __bf16* WT       = (__bf16*)(ws + 64 * MB);    // 2MB  512x2048
    __bf16* WcatT    = (__bf16*)(ws + 66 * MB);    // 1MB  1024x512
    __bf16* cdT      = (__bf16*)(ws + 67 * MB);    // 0.5MB
    __bf16* cwT      = (__bf16*)(ws + 67 * MB + 512 * 1024);
    __bf16* kernT    = (__bf16*)(ws + 68 * MB);    // 1.5MB 1536x512
    __bf16* rkernT   = (__bf16*)(ws + 69 * MB + 512 * 1024);  // ends 71MB

    float* h_out   = (float*)d_out;
    float* cro_out = (float*)d_out + 2 * 1048576;

    const int BIG = 1 << 30;

    prep_wT<<<896, 256, 0, stream>>>(ew1, ew2, ca12w, ca12u, ca12v, ca21w,
                                     ca21u, ca21v, cd_w, cw_w, kern, rkern,
                                     WT, WcatT, cdT, cwT, kernT, rkernT);

    // Phase A (AFP32): G12 -> E bf16 direct; G4 -> cro_bf = tanh(.+cd_b)  [512]
    SubGemm gA1 = { inputs, 4000, 2000, WT,  2048, nullptr, E,      512, 2048, 4, 2,   2000, 1, nullptr, nullptr, nullptr, nullptr };
    SubGemm gA2 = { crohis,  512,  512, cdT,  512, nullptr, cro_bf, 512,  512, 4, BIG, 0,    3, cd_b,    nullptr, nullptr, nullptr };
    gemm_dual<true><<<dim3(8, 64), 256, 0, stream>>>(gA1, gA2, 4);

    // Phase B: G3 -> T bf16; G5 -> hprev = h_tm1 + tanh(.+cw_b) (f32+bf16) [768]
    SubGemm gB1 = { E,      512, 512, WcatT, 512, nullptr, T,        1024, 512, 8, BIG, 0, 1, nullptr, nullptr, nullptr, nullptr };
    SubGemm gB2 = { cro_bf, 512, 512, cwT,   512, hprev,   hprev_bf, 512,  512, 4, BIG, 0, 4, cw_b,    h_tm1,   nullptr, nullptr };
    gemm_dual<false><<<dim3(12, 64), 256, 0, stream>>>(gB1, gB2, 8);

    // attention -> x, crohis_new
    fuse_att<<<4096, 256, 0, stream>>>(T, E, crohis, x, cro_out);

    // Phase C: G6 -> mx_bf (= acc + bias, bf16); G7 -> mi2_bf           [1280]
    SubGemm gC1 = { x,        512, 512, kernT,  512, nullptr, mx_bf,  1536, 512, 12, BIG, 0, 2, bias,    nullptr, nullptr, nullptr };
    SubGemm gC2 = { hprev_bf, 512, 512, rkernT, 512, nullptr, mi2_bf, 1024, 512, 8,  BIG, 0, 1, nullptr, nullptr, nullptr, nullptr };
    gemm_dual<false><<<dim3(20, 64), 256, 0, stream>>>(gC1, gC2, 12);

    // gates -> rh
    gates_k<<<2048, 256, 0, stream>>>(mx_bf, mi2_bf, hprev_bf, rh);

    // G8 + fused GRU final -> h                                          [256]
    SubGemm gG = { rh, 512, 512, rkernT + (size_t)1024 * 512, 512, h_out, nullptr, 512, 512, 4, BIG, 0, 5, nullptr, hprev, mx_bf, mi2_bf };
    gemm_dual<false><<<dim3(4, 64), 256, 0, stream>>>(gG, gG, 4);
}

// Round 14
// 142.159 us; speedup vs baseline: 1.6497x; 1.2311x over previous
//
#include <hip/hip_runtime.h>
#include <hip/hip_bf16.h>
#include <math.h>

// DscaGRUCell rev 14 — rev 10 baseline (132.7 us) with ONE change: dedicated
// lean input-conversion kernel (Xb 4096x4096 bf16 zero-padded + crohis_bf) so
// ALL GEMM phases use the proven bf16 depth-3 vmcnt(6) pipeline. fp32-A path
// deleted. Everything else identical to rev 10.

#define TAU_F 0.5f

typedef __bf16 bf16x8 __attribute__((ext_vector_type(8)));
typedef __bf16 bf16x4 __attribute__((ext_vector_type(4)));
typedef float f32x4 __attribute__((ext_vector_type(4)));

__device__ __forceinline__ void gload16(const void* g, void* l) {
    __builtin_amdgcn_global_load_lds(
        (const __attribute__((address_space(1))) void*)g,
        (__attribute__((address_space(3))) void*)l, 16, 0, 0);
}

struct SubGemm {
    const __bf16* A;  // M x lda row-major bf16 (zero-padded where needed)
    int lda;
    const __bf16* BT; // N x Kpad row-major (pre-transposed, zero-padded bf16)
    int ldbt;
    float* C;         // out base (fp32 partials, or bf16 when obf16)
    int ldc;
    long long strideC;
    int Ksub;         // K per split slice (mult of 32)
    int nbx;          // col tiles (N/128)
    int pairSplit;    // ct >= this uses A + pairAOff
    int pairAOff;
    int obf16;
};

// 64x128 tile, BK=32, 4 waves (2x4 frags of 16x16x32 bf16 MFMA).
// 4 LDS bufs, depth 3, 3 gload_lds/step, wait vmcnt(6) (loads aged 3 steps).
__global__ __launch_bounds__(256) void gemm_dual(SubGemm g1, SubGemm g2, int blocks1)
{
    __shared__ __attribute__((aligned(16))) char lds[49152];

    const int tid = threadIdx.x, w = tid >> 6, l = tid & 63;

    // T1 XCD-chunked swizzle (nwg % 8 == 0 for all launches here)
    const int gx = gridDim.x;
    const int nwg = gx * (int)gridDim.y;
    const int hw = (int)blockIdx.y * gx + (int)blockIdx.x;
    const int lg = (hw & 7) * (nwg >> 3) + (hw >> 3);
    const int bxl_lin = lg % gx;
    const int by = lg / gx;

    const bool second = bxl_lin >= blocks1;
    const SubGemm& g = second ? g2 : g1;
    const int bxl = second ? bxl_lin - blocks1 : bxl_lin;
    const int ct = bxl % g.nbx, spl = bxl / g.nbx;
    const int brow = by * 64, bcol = ct * 128;
    const int k_begin = spl * g.Ksub;
    const int nt = g.Ksub >> 5;
    const int aoff = (ct >= g.pairSplit) ? g.pairAOff : 0;

    const int sbr = w * 32 + (l >> 2);        // B staging rows (2 issues)
    const int seg = (l & 3) * 8;

    const __bf16* Bg0 = g.BT + (size_t)(bcol + sbr) * g.ldbt + seg + k_begin;
    const __bf16* Bg1 = Bg0 + (size_t)16 * g.ldbt;

    f32x4 acc[2][4] = {};
    const int fr = l & 15, fk = (l >> 4) * 8;
    const int wr = (w >> 1) * 32, wc = (w & 1) * 64;
    const int kmax = (nt - 1) * 32;

    // LDS: As 4 x [64][32] bf16 (16KB) | Bs 4 x [128][32] bf16 (32KB)
    auto As = (__bf16 (*)[64][32])lds;
    auto Bs = (__bf16 (*)[128][32])(lds + 16384);

    const int sar = w * 16 + (l >> 2);
    const __bf16* Ar = g.A + aoff + (size_t)(brow + sar) * g.lda + seg + k_begin;

#define ISSUE_AB(slot)                                                        \
    {                                                                         \
        const int _s = (slot);                                                \
        const int _k = (_s * 32 < kmax) ? _s * 32 : kmax;                     \
        const int _b = _s & 3;                                                \
        gload16(Ar + _k,  &As[_b][w * 16][0]);                                \
        gload16(Bg0 + _k, &Bs[_b][w * 32][0]);                                \
        gload16(Bg1 + _k, &Bs[_b][w * 32 + 16][0]);                           \
    }

    ISSUE_AB(0) ISSUE_AB(1) ISSUE_AB(2)

    for (int t = 0; t < nt; ++t) {
        asm volatile("s_waitcnt vmcnt(6)" ::: "memory");
        asm volatile("s_waitcnt lgkmcnt(0)" ::: "memory");
        __builtin_amdgcn_s_barrier();

        const int bi = t & 3;
        bf16x8 a[2], b[4];
#pragma unroll
        for (int m = 0; m < 2; ++m) a[m] = *(const bf16x8*)&As[bi][wr + m * 16 + fr][fk];
#pragma unroll
        for (int n = 0; n < 4; ++n) b[n] = *(const bf16x8*)&Bs[bi][wc + n * 16 + fr][fk];

        ISSUE_AB(t + 3)

#pragma unroll
        for (int m = 0; m < 2; ++m)
#pragma unroll
            for (int n = 0; n < 4; ++n)
                acc[m][n] = __builtin_amdgcn_mfma_f32_16x16x32_bf16(a[m], b[n], acc[m][n], 0, 0, 0);
    }
#undef ISSUE_AB

    // epilogue. C/D: col=lane&15, row=(lane>>4)*4+reg
    const int fq = (l >> 4) * 4;
    if (g.obf16) {
        __bf16* Cb = (__bf16*)g.C + (size_t)spl * g.strideC;
#pragma unroll
        for (int m = 0; m < 2; ++m)
#pragma unroll
            for (int n = 0; n < 4; ++n)
#pragma unroll
                for (int r = 0; r < 4; ++r) {
                    int row = brow + wr + m * 16 + fq + r;
                    int col = bcol + wc + n * 16 + fr;
                    Cb[(size_t)row * g.ldc + col] = (__bf16)acc[m][n][r];
                }
    } else {
        float* C = g.C + (size_t)spl * g.strideC;
#pragma unroll
        for (int m = 0; m < 2; ++m)
#pragma unroll
            for (int n = 0; n < 4; ++n)
#pragma unroll
                for (int r = 0; r < 4; ++r) {
                    int row = brow + wr + m * 16 + fq + r;
                    int col = bcol + wc + n * 16 + fr;
                    C[(size_t)row * g.ldc + col] = acc[m][n][r];
                }
    }
}

// ---------------- cvt_in: inputs -> Xb (4096x4096 bf16, zero-padded) + crohis_bf
__global__ __launch_bounds__(256) void cvt_in(
    const float* __restrict__ inputs, const float* __restrict__ crohis,
    __bf16* __restrict__ Xb, __bf16* __restrict__ crohis_bf)
{
    int i = blockIdx.x * 256 + threadIdx.x;
    if (i < 2097152) {                       // Xb: 4096 rows x 512 chunks of 8
        int r = i >> 9, c = (i & 511) * 8;
        f32x4 v0 = {0, 0, 0, 0}, v1 = {0, 0, 0, 0};
        if (c < 2000) {
            const float* p = inputs + (size_t)r * 4000 + c;
            v0 = *(const f32x4*)p; v1 = *(const f32x4*)(p + 4);
        } else if (c >= 2048 && c < 4048) {
            const float* p = inputs + (size_t)r * 4000 + 2000 + (c - 2048);
            v0 = *(const f32x4*)p; v1 = *(const f32x4*)(p + 4);
        }
        __bf16 o[8];
#pragma unroll
        for (int z = 0; z < 4; ++z) { o[z] = (__bf16)v0[z]; o[4 + z] = (__bf16)v1[z]; }
        *(bf16x8*)(Xb + (size_t)r * 4096 + c) = *(bf16x8*)o;
        return;
    }
    i -= 2097152;
    if (i < 262144) {                        // crohis: 2M elems / 8
        int e = i * 8;
        const float* p = crohis + e;
        f32x4 v0 = *(const f32x4*)p, v1 = *(const f32x4*)(p + 4);
        __bf16 o[8];
#pragma unroll
        for (int z = 0; z < 4; ++z) { o[z] = (__bf16)v0[z]; o[4 + z] = (__bf16)v1[z]; }
        *(bf16x8*)(crohis_bf + e) = *(bf16x8*)o;
    }
}

// ---------------- prep: LDS-tiled weight transposes --------------------------
__global__ __launch_bounds__(256) void prep_wT(
    const float* __restrict__ ew1, const float* __restrict__ ew2,
    const float* __restrict__ w12, const float* __restrict__ u12,
    const float* __restrict__ v12, const float* __restrict__ w21,
    const float* __restrict__ u21, const float* __restrict__ v21,
    const float* __restrict__ cd_w, const float* __restrict__ cw_w,
    const float* __restrict__ kern, const float* __restrict__ rkern,
    __bf16* __restrict__ WT, __bf16* __restrict__ WcatT,
    __bf16* __restrict__ cdT, __bf16* __restrict__ cwT,
    __bf16* __restrict__ kernT, __bf16* __restrict__ rkernT)
{
    __shared__ float tile[64][65];
    const int b = blockIdx.x, tid = threadIdx.x;
    const int tr = tid >> 6, tc = tid & 63;

    const float* src = nullptr;
    int ldsrc = 0, srow0 = 0, scol0 = 0, kvalid = 1 << 30;
    __bf16* dst; int ldd, n0, k0;
    bool zero = false;

    if (b < 256) {                         // WT: out 512 x 2048
        int q = b; n0 = (q >> 5) * 64; k0 = (q & 31) * 64;
        dst = WT; ldd = 2048; kvalid = 2000; ldsrc = 256; srow0 = k0;
        if (n0 < 256) { src = ew1; scol0 = n0; } else { src = ew2; scol0 = n0 - 256; }
    } else if (b < 384) {                  // WcatT: out 1024 x 512
        int q = b - 256; n0 = (q >> 3) * 64; k0 = (q & 7) * 64;
        dst = WcatT; ldd = 512; ldsrc = 256; srow0 = k0 & 255; scol0 = n0 & 255;
        int qn = n0 >> 8; bool khi = k0 >= 256;
        if (qn == 0)      src = khi ? u12 : w12;
        else if (qn == 1) src = khi ? w21 : u21;
        else if (qn == 2) { if (khi) src = v12; else zero = true; }
        else              { if (khi) zero = true; else src = v21; }
    } else if (b < 448) {                  // cdT
        int q = b - 384; n0 = (q >> 3) * 64; k0 = (q & 7) * 64;
        src = cd_w; ldsrc = 512; srow0 = k0; scol0 = n0; dst = cdT; ldd = 512;
    } else if (b < 512) {                  // cwT
        int q = b - 448; n0 = (q >> 3) * 64; k0 = (q & 7) * 64;
        src = cw_w; ldsrc = 512; srow0 = k0; scol0 = n0; dst = cwT; ldd = 512;
    } else if (b < 704) {                  // kernT
        int q = b - 512; n0 = (q >> 3) * 64; k0 = (q & 7) * 64;
        src = kern; ldsrc = 1536; srow0 = k0; scol0 = n0; dst = kernT; ldd = 512;
    } else {                               // rkernT
        int q = b - 704; n0 = (q >> 3) * 64; k0 = (q & 7) * 64;
        src = rkern; ldsrc = 1536; srow0 = k0; scol0 = n0; dst = rkernT; ldd = 512;
    }

#pragma unroll
    for (int p = 0; p < 16; ++p) {
        int kr = p * 4 + tr;
        float v = 0.f;
        if (!zero && (srow0 + kr) < kvalid)
            v = src[(size_t)(srow0 + kr) * ldsrc + scol0 + tc];
        tile[kr][tc] = v;
    }
    __syncthreads();
#pragma unroll
    for (int p = 0; p < 16; ++p) {
        int nr = p * 4 + tr;
        dst[(size_t)(n0 + nr) * ldd + k0 + tc] = (__bf16)tile[tc][nr];
    }
}

// ---------------- R-A: E = bf16(sum2 P12), cro = bf16(tanh(P4 + cd_b)) ------
__global__ __launch_bounds__(256) void reduce_A(
    const float* __restrict__ P12, const float* __restrict__ P4,
    const float* __restrict__ cd_b,
    __bf16* __restrict__ E, __bf16* __restrict__ cro)
{
    const int S = 1 << 21;
    int b = blockIdx.x;
    int i = (((b & 2047) * 256) + threadIdx.x) * 4;
    if (b < 2048) {
        f32x4 p0 = *(const f32x4*)(P12 + i);
        f32x4 p1 = *(const f32x4*)(P12 + S + i);
        __bf16 o[4];
#pragma unroll
        for (int j = 0; j < 4; ++j) o[j] = (__bf16)(p0[j] + p1[j]);
        *(bf16x4*)&E[i] = *(bf16x4*)o;
    } else {
        f32x4 p0 = *(const f32x4*)(P4 + i);
        int c = i & 511;
        __bf16 o[4];
#pragma unroll
        for (int j = 0; j < 4; ++j) o[j] = (__bf16)tanhf(p0[j] + cd_b[c + j]);
        *(bf16x4*)&cro[i] = *(bf16x4*)o;
    }
}

// ---------------- fuse1: attention + x + crohis_new, and hprev ---------------
__global__ __launch_bounds__(256) void fuse1(
    const __bf16* __restrict__ T, const __bf16* __restrict__ E,
    const float* __restrict__ crohis,
    const float* __restrict__ P5,
    const float* __restrict__ h_tm1, const float* __restrict__ cw_b,
    __bf16* __restrict__ x, float* __restrict__ cro_out,
    float* __restrict__ hprev, __bf16* __restrict__ hprev_bf)
{
    __shared__ float s4[4];
    int b = blockIdx.x;
    int j = threadIdx.x;
    if (b < 4096) {
        const __bf16* t = T + (size_t)b * 1024;
        float s12 = tanhf((float)t[j])       * (float)t[512 + j];
        float s21 = tanhf((float)t[256 + j]) * (float)t[768 + j];
        float v = s12;
#pragma unroll
        for (int o = 32; o >= 1; o >>= 1) v = fmaxf(v, __shfl_xor(v, o, 64));
        __syncthreads(); if ((j & 63) == 0) s4[j >> 6] = v; __syncthreads();
        float m12 = fmaxf(fmaxf(s4[0], s4[1]), fmaxf(s4[2], s4[3]));
        float e12 = expf(s12 - m12);
        v = e12;
#pragma unroll
        for (int o = 32; o >= 1; o >>= 1) v += __shfl_xor(v, o, 64);
        __syncthreads(); if ((j & 63) == 0) s4[j >> 6] = v; __syncthreads();
        float sum12 = s4[0] + s4[1] + s4[2] + s4[3];
        v = s21;
#pragma unroll
        for (int o = 32; o >= 1; o >>= 1) v = fmaxf(v, __shfl_xor(v, o, 64));
        __syncthreads(); if ((j & 63) == 0) s4[j >> 6] = v; __syncthreads();
        float m21 = fmaxf(fmaxf(s4[0], s4[1]), fmaxf(s4[2], s4[3]));
        float e21 = expf(s21 - m21);
        v = e21;
#pragma unroll
        for (int o = 32; o >= 1; o >>= 1) v += __shfl_xor(v, o, 64);
        __syncthreads(); if ((j & 63) == 0) s4[j >> 6] = v; __syncthreads();
        float sum21 = s4[0] + s4[1] + s4[2] + s4[3];

        size_t b0 = (size_t)b * 512 + j, b1 = b0 + 256;
        float x1 = (float)E[b0] * (e12 / sum12);
        float x2 = (float)E[b1] * (e21 / sum21);
        x[b0] = (__bf16)x1;
        x[b1] = (__bf16)x2;
        cro_out[b0] = TAU_F * crohis[b0] + (1.f - TAU_F) * x1;
        cro_out[b1] = TAU_F * crohis[b1] + (1.f - TAU_F) * x2;
    } else {
        int i = ((b - 4096) * 256 + j) * 4;
        f32x4 p = *(const f32x4*)(P5 + i);
        f32x4 ht = *(const f32x4*)(h_tm1 + i);
        int c = i & 511;
        f32x4 o; __bf16 ob[4];
#pragma unroll
        for (int q = 0; q < 4; ++q) {
            float hv = ht[q] + tanhf(p[q] + cw_b[c + q]);
            o[q] = hv; ob[q] = (__bf16)hv;
        }
        *(f32x4*)(hprev + i) = o;
        *(bf16x4*)&hprev_bf[i] = *(bf16x4*)ob;
    }
}

// ---------------- gates: rh = sigmoid(mx_r + bias_r + mi_r) * hprev ----------
__global__ __launch_bounds__(256) void gates_k(
    const float* __restrict__ mx, const float* __restrict__ mi2,
    const float* __restrict__ hprev, const float* __restrict__ bias,
    __bf16* __restrict__ rh)
{
    int i = (blockIdx.x * 256 + threadIdx.x) * 4;
    int row = i >> 9, c = i & 511;
    f32x4 a  = *(const f32x4*)(mx + (size_t)row * 1536 + 512 + c);
    f32x4 m  = *(const f32x4*)(mi2 + (size_t)row * 1024 + 512 + c);
    f32x4 hp = *(const f32x4*)(hprev + i);
    f32x4 bb = *(const f32x4*)(bias + 512 + c);
    __bf16 o[4];
#pragma unroll
    for (int q = 0; q < 4; ++q) {
        float r = 1.f / (1.f + expf(-(a[q] + bb[q] + m[q])));
        o[q] = (__bf16)(r * hp[q]);
    }
    *(bf16x4*)&rh[i] = *(bf16x4*)o;
}

// ---------------- final: h ---------------------------------------------------
__global__ __launch_bounds__(256) void final_k(
    const float* __restrict__ mx, const float* __restrict__ mi2,
    const float* __restrict__ P8a, const float* __restrict__ P8b,
    const float* __restrict__ hprev, const float* __restrict__ bias,
    float* __restrict__ h)
{
    int i = (blockIdx.x * 256 + threadIdx.x) * 4;
    int row = i >> 9, c = i & 511;
    f32x4 xz = *(const f32x4*)(mx + (size_t)row * 1536 + c);
    f32x4 xh = *(const f32x4*)(mx + (size_t)row * 1536 + 1024 + c);
    f32x4 mz = *(const f32x4*)(mi2 + (size_t)row * 1024 + c);
    f32x4 p0 = *(const f32x4*)(P8a + i);
    f32x4 p1 = *(const f32x4*)(P8b + i);
    f32x4 hp = *(const f32x4*)(hprev + i);
    f32x4 bz = *(const f32x4*)(bias + c);
    f32x4 bh = *(const f32x4*)(bias + 1024 + c);
    f32x4 o;
#pragma unroll
    for (int q = 0; q < 4; ++q) {
        float z = 1.f / (1.f + expf(-(xz[q] + bz[q] + mz[q])));
        float hh = tanhf(xh[q] + bh[q] + p0[q] + p1[q]);
        o[q] = z * hp[q] + (1.f - z) * hh;
    }
    *(f32x4*)(h + i) = o;
}

// ---------------- launch -----------------------------------------------------
extern "C" void kernel_launch(void* const* d_in, const int* in_sizes, int n_in,
                              void* d_out, int out_size, void* d_ws, size_t ws_size,
                              hipStream_t stream)
{
    (void)in_sizes; (void)n_in; (void)out_size; (void)ws_size;

    const float* inputs = (const float*)d_in[0];
    const float* h_tm1  = (const float*)d_in[1];
    const float* crohis = (const float*)d_in[2];
    const float* ew1    = (const float*)d_in[3];
    const float* ew2    = (const float*)d_in[4];
    const float* ca12w  = (const float*)d_in[5];
    const float* ca12u  = (const float*)d_in[6];
    const float* ca12v  = (const float*)d_in[7];
    const float* ca21w  = (const float*)d_in[8];
    const float* ca21u  = (const float*)d_in[9];
    const float* ca21v  = (const float*)d_in[10];
    const float* cw_w   = (const float*)d_in[11];
    const float* cw_b   = (const float*)d_in[12];
    const float* cd_w   = (const float*)d_in[13];
    const float* cd_b   = (const float*)d_in[14];
    const float* kern   = (const float*)d_in[15];
    const float* rkern  = (const float*)d_in[16];
    const float* bias   = (const float*)d_in[17];

    char* ws = (char*)d_ws;
    const size_t MB = 1 << 20;
    // layout (lifetimes verified disjoint):
    //  0-16  P12 x2 [A]                 -> mx @0-24 [C..final]
    // 16-24  P4 [A] -> T bf16 [B..fuse1]   (mx covers 16-24 after fuse1)
    // 24-56  Xb [cvt..A]; P5 @32-40 [B..fuse1]; mi2 @24-40 [C..final]
    // 40-44  x [fuse1..C] -> rh [gates..G8]
    // 44-52  P8 s0 [G8..final] (44-48 free, 48-52 over dead E)
    // 48-52  E [redA..fuse1]
    // 52-60  P8 s1 [G8..final] (52-56 over dead cro_bf, 56-60 over dead crohis_bf)
    // 52-56  cro_bf [redA..B]
    // 56-60  crohis_bf [cvt..A]
    // 60-68  hprev [fuse1..final]
    // 68-72  hprev_bf [fuse1..C]
    // 72-79  weights
    float*  P12       = (float*)(ws + 0);
    float*  P4        = (float*)(ws + 16 * MB);
    __bf16* T         = (__bf16*)(ws + 16 * MB);
    __bf16* Xb        = (__bf16*)(ws + 24 * MB);
    float*  P5        = (float*)(ws + 32 * MB);
    __bf16* x         = (__bf16*)(ws + 40 * MB);
    __bf16* rh        = (__bf16*)(ws + 40 * MB);
    float*  P8        = (float*)(ws + 44 * MB);
    __bf16* E         = (__bf16*)(ws + 48 * MB);
    __bf16* cro_bf    = (__bf16*)(ws + 52 * MB);
    __bf16* crohis_bf = (__bf16*)(ws + 56 * MB);
    float*  hprev     = (float*)(ws + 60 * MB);
    __bf16* hprev_bf  = (__bf16*)(ws + 68 * MB);
    float*  mx        = (float*)(ws + 0);
    float*  mi2       = (float*)(ws + 24 * MB);
    __bf16* WT        = (__bf16*)(ws + 72 * MB);               // 2MB
    __bf16* WcatT     = (__bf16*)(ws + 74 * MB);               // 1MB
    __bf16* cdT       = (__bf16*)(ws + 75 * MB);               // 0.5MB
    __bf16* cwT       = (__bf16*)(ws + 75 * MB + 512 * 1024);  // 0.5MB
    __bf16* kernT     = (__bf16*)(ws + 76 * MB);               // 1.5MB
    __bf16* rkernT    = (__bf16*)(ws + 77 * MB + 512 * 1024);  // ends 79MB

    float* h_out   = (float*)d_out;
    float* cro_out = (float*)d_out + 2 * 1048576;

    const int BIG = 1 << 30;
    const long long S2 = 1ll << 21;   // 8MB slice stride (fp32 elems)

    prep_wT<<<896, 256, 0, stream>>>(ew1, ew2, ca12w, ca12u, ca12v, ca21w,
                                     ca21u, ca21v, cd_w, cw_w, kern, rkern,
                                     WT, WcatT, cdT, cwT, kernT, rkernT);

    cvt_in<<<9216, 256, 0, stream>>>(inputs, crohis, Xb, crohis_bf);

    // Phase A (all-bf16): G12 split-2 over Xb + G4 over crohis_bf  [grid (12,64)=768]
    SubGemm gA1 = { Xb,        4096, WT,  2048, P12, 512, S2, 1024, 4, 2,   2048, 0 };
    SubGemm gA2 = { crohis_bf,  512, cdT,  512, P4,  512, 0,   512, 4, BIG, 0,    0 };
    gemm_dual<<<dim3(12, 64), 256, 0, stream>>>(gA1, gA2, 8);

    reduce_A<<<4096, 256, 0, stream>>>(P12, P4, cd_b, E, cro_bf);

    // Phase B: G3 (bf16 T out) + G5                                 [grid (12,64)=768]
    SubGemm gB1 = { E,      512, WcatT, 512, (float*)T, 1024, 0, 512, 8, BIG, 0, 1 };
    SubGemm gB2 = { cro_bf, 512, cwT,   512, P5,        512,  0, 512, 4, BIG, 0, 0 };
    gemm_dual<<<dim3(12, 64), 256, 0, stream>>>(gB1, gB2, 8);

    fuse1<<<6144, 256, 0, stream>>>(T, E, crohis, P5, h_tm1, cw_b,
                                    x, cro_out, hprev, hprev_bf);

    // Phase C: G6 (mx) + G7 (mi2)                                    [grid (20,64)=1280]
    SubGemm gC1 = { x,        512, kernT,  512, mx,  1536, 0, 512, 12, BIG, 0, 0 };
    SubGemm gC2 = { hprev_bf, 512, rkernT, 512, mi2, 1024, 0, 512, 8,  BIG, 0, 0 };
    gemm_dual<<<dim3(20, 64), 256, 0, stream>>>(gC1, gC2, 12);

    gates_k<<<2048, 256, 0, stream>>>(mx, mi2, hprev, bias, rh);

    // G8: split-2                                                    [grid (8,64)=512]
    SubGemm gG = { rh, 512, rkernT + (size_t)1024 * 512, 512, P8, 512, S2, 256, 4, BIG, 0, 0 };
    gemm_dual<<<dim3(8, 64), 256, 0, stream>>>(gG, gG, 8);

    final_k<<<2048, 256, 0, stream>>>(mx, mi2, P8, P8 + S2, hprev, bias, h_out);
}

// Round 15
// 132.068 us; speedup vs baseline: 1.7758x; 1.0764x over previous
//
#include <hip/hip_runtime.h>
#include <hip/hip_bf16.h>
#include <math.h>

// DscaGRUCell rev 15 — rev 10 (132.7us, best) + ONE change: G8 gets a
// dedicated GEMM kernel with the GRU finalization fused into its epilogue
// (deletes final_k and the P8 partial buffers). Shared gemm_dual untouched.

#define TAU_F 0.5f

typedef __bf16 bf16x8 __attribute__((ext_vector_type(8)));
typedef __bf16 bf16x4 __attribute__((ext_vector_type(4)));
typedef float f32x4 __attribute__((ext_vector_type(4)));

__device__ __forceinline__ void gload16(const void* g, void* l) {
    __builtin_amdgcn_global_load_lds(
        (const __attribute__((address_space(1))) void*)g,
        (__attribute__((address_space(3))) void*)l, 16, 0, 0);
}

struct SubGemm {
    const void* A;    // M x lda (f32 if AFP32 else bf16)
    int lda;
    int Kvalid;       // AFP32: valid A cols (addr clamp; BT zero-padded beyond)
    const __bf16* BT; // N x Kpad row-major (pre-transposed, zero-padded bf16)
    int ldbt;
    float* C;         // out base (fp32, or bf16 when obf16)
    int ldc;
    long long strideC;
    int Ksub;         // K per split slice (mult of 32)
    int nbx;          // col tiles (N/128)
    int pairSplit;    // ct >= this uses A + pairAOff
    int pairAOff;
    int obf16;        // store bf16 instead of f32
};

// 64x128 tile, BK=32, 4 waves (2x4 frags of 16x16x32 bf16 MFMA).
// bf16 path:  4 LDS bufs, depth 3, 3 gload_lds/step, wait vmcnt(6).
// AFP32 path: A staged RAW FP32 via gload_lds; cvt at fragment-read time.
template <bool AFP32>
__global__ __launch_bounds__(256) void gemm_dual(SubGemm g1, SubGemm g2, int blocks1)
{
    __shared__ __attribute__((aligned(16))) char lds[49152];

    const int tid = threadIdx.x, w = tid >> 6, l = tid & 63;

    // T1 XCD-chunked swizzle (nwg % 8 == 0 for all launches here)
    const int gx = gridDim.x;
    const int nwg = gx * (int)gridDim.y;
    const int hw = (int)blockIdx.y * gx + (int)blockIdx.x;
    const int lg = (hw & 7) * (nwg >> 3) + (hw >> 3);
    const int bxl_lin = lg % gx;
    const int by = lg / gx;

    const bool second = bxl_lin >= blocks1;
    const SubGemm& g = second ? g2 : g1;
    const int bxl = second ? bxl_lin - blocks1 : bxl_lin;
    const int ct = bxl % g.nbx, spl = bxl / g.nbx;
    const int brow = by * 64, bcol = ct * 128;
    const int k_begin = spl * g.Ksub;
    const int nt = g.Ksub >> 5;
    const int aoff = (ct >= g.pairSplit) ? g.pairAOff : 0;

    const int sbr = w * 32 + (l >> 2);        // B staging rows (2 issues)
    const int seg = (l & 3) * 8;

    const __bf16* Bg0 = g.BT + (size_t)(bcol + sbr) * g.ldbt + seg + k_begin;
    const __bf16* Bg1 = Bg0 + (size_t)16 * g.ldbt;

    f32x4 acc[2][4] = {};
    const int fr = l & 15, fk = (l >> 4) * 8;
    const int wr = (w >> 1) * 32, wc = (w & 1) * 64;
    const int kmax = (nt - 1) * 32;

    if constexpr (AFP32) {
        // LDS: Af32 3 x [64][32] f32 (24KB) | Bs 3 x [128][32] bf16 (24KB)
        auto Af32 = (float (*)[64][32])lds;
        auto Bs   = (__bf16 (*)[128][32])(lds + 24576);

        const float* ArowBase = (const float*)g.A + aoff
                              + (size_t)(brow + w * 16 + (l >> 3)) * g.lda;
        const int colLane = (l & 7) * 4;
        const int kcl4 = g.Kvalid - 4;

#define ISSUE_A32(slot)                                                       \
        {                                                                     \
            const int _s = (slot);                                            \
            const int _k = (_s * 32 < kmax) ? _s * 32 : kmax;                 \
            const int _b = _s % 3;                                            \
            int c0 = k_begin + _k + colLane;                                  \
            c0 = c0 < kcl4 ? c0 : kcl4;                                       \
            gload16(ArowBase + c0,                 &Af32[_b][w * 16][0]);     \
            gload16(ArowBase + 8 * g.lda + c0,     &Af32[_b][w * 16 + 8][0]); \
            gload16(Bg0 + _k, &Bs[_b][w * 32][0]);                            \
            gload16(Bg1 + _k, &Bs[_b][w * 32 + 16][0]);                       \
        }

        ISSUE_A32(0) ISSUE_A32(1)

        for (int t = 0; t < nt; ++t) {
            asm volatile("s_waitcnt vmcnt(4)" ::: "memory");
            asm volatile("s_waitcnt lgkmcnt(0)" ::: "memory");
            __builtin_amdgcn_s_barrier();

            const int bi = t % 3;
            bf16x8 a[2]; bf16x8 b[4];
#pragma unroll
            for (int m = 0; m < 2; ++m) {
                f32x4 lo = *(const f32x4*)&Af32[bi][wr + m * 16 + fr][fk];
                f32x4 hi = *(const f32x4*)&Af32[bi][wr + m * 16 + fr][fk + 4];
#pragma unroll
                for (int z = 0; z < 4; ++z) { a[m][z] = (__bf16)lo[z]; a[m][4 + z] = (__bf16)hi[z]; }
            }
#pragma unroll
            for (int n = 0; n < 4; ++n) b[n] = *(const bf16x8*)&Bs[bi][wc + n * 16 + fr][fk];

            ISSUE_A32(t + 2)

#pragma unroll
            for (int m = 0; m < 2; ++m)
#pragma unroll
                for (int n = 0; n < 4; ++n)
                    acc[m][n] = __builtin_amdgcn_mfma_f32_16x16x32_bf16(a[m], b[n], acc[m][n], 0, 0, 0);
        }
#undef ISSUE_A32
    } else {
        // LDS: As 4 x [64][32] bf16 (16KB) | Bs 4 x [128][32] bf16 (32KB)
        auto As = (__bf16 (*)[64][32])lds;
        auto Bs = (__bf16 (*)[128][32])(lds + 16384);

        const int sar = w * 16 + (l >> 2);
        const __bf16* Ar = (const __bf16*)g.A + aoff
                         + (size_t)(brow + sar) * g.lda + seg + k_begin;

#define ISSUE_AB(slot)                                                        \
        {                                                                     \
            const int _s = (slot);                                            \
            const int _k = (_s * 32 < kmax) ? _s * 32 : kmax;                 \
            const int _b = _s & 3;                                            \
            gload16(Ar + _k,  &As[_b][w * 16][0]);                            \
            gload16(Bg0 + _k, &Bs[_b][w * 32][0]);                            \
            gload16(Bg1 + _k, &Bs[_b][w * 32 + 16][0]);                       \
        }

        ISSUE_AB(0) ISSUE_AB(1) ISSUE_AB(2)

        for (int t = 0; t < nt; ++t) {
            asm volatile("s_waitcnt vmcnt(6)" ::: "memory");
            asm volatile("s_waitcnt lgkmcnt(0)" ::: "memory");
            __builtin_amdgcn_s_barrier();

            const int bi = t & 3;
            bf16x8 a[2], b[4];
#pragma unroll
            for (int m = 0; m < 2; ++m) a[m] = *(const bf16x8*)&As[bi][wr + m * 16 + fr][fk];
#pragma unroll
            for (int n = 0; n < 4; ++n) b[n] = *(const bf16x8*)&Bs[bi][wc + n * 16 + fr][fk];

            ISSUE_AB(t + 3)

#pragma unroll
            for (int m = 0; m < 2; ++m)
#pragma unroll
                for (int n = 0; n < 4; ++n)
                    acc[m][n] = __builtin_amdgcn_mfma_f32_16x16x32_bf16(a[m], b[n], acc[m][n], 0, 0, 0);
        }
#undef ISSUE_AB
    }

    // epilogue. C/D: col=lane&15, row=(lane>>4)*4+reg
    const int fq = (l >> 4) * 4;
    if (g.obf16) {
        __bf16* Cb = (__bf16*)g.C + (size_t)spl * g.strideC;
#pragma unroll
        for (int m = 0; m < 2; ++m)
#pragma unroll
            for (int n = 0; n < 4; ++n)
#pragma unroll
                for (int r = 0; r < 4; ++r) {
                    int row = brow + wr + m * 16 + fq + r;
                    int col = bcol + wc + n * 16 + fr;
                    Cb[(size_t)row * g.ldc + col] = (__bf16)acc[m][n][r];
                }
    } else {
        float* C = g.C + (size_t)spl * g.strideC;
#pragma unroll
        for (int m = 0; m < 2; ++m)
#pragma unroll
            for (int n = 0; n < 4; ++n)
#pragma unroll
                for (int r = 0; r < 4; ++r) {
                    int row = brow + wr + m * 16 + fq + r;
                    int col = bcol + wc + n * 16 + fr;
                    C[(size_t)row * g.ldc + col] = acc[m][n][r];
                }
    }
}

// ---------------- G8 + fused GRU final: h = z*hprev + (1-z)*tanh(xh+acc) ----
// Dedicated kernel (keeps shared gemm_dual codegen untouched). A = rh bf16
// (4096x512), BT = rkernT cols 1024:1536 (512x512), K=512, grid (4,64).
__global__ __launch_bounds__(256) void gemm_g8(
    const __bf16* __restrict__ A, const __bf16* __restrict__ BT,
    const float* __restrict__ mx, const float* __restrict__ mi2,
    const float* __restrict__ hprev, const float* __restrict__ bias,
    float* __restrict__ h)
{
    __shared__ __attribute__((aligned(16))) char lds[49152];

    const int tid = threadIdx.x, w = tid >> 6, l = tid & 63;

    const int gx = gridDim.x;
    const int nwg = gx * (int)gridDim.y;
    const int hw = (int)blockIdx.y * gx + (int)blockIdx.x;
    const int lg = (hw & 7) * (nwg >> 3) + (hw >> 3);
    const int ct = lg % gx;
    const int by = lg / gx;

    const int brow = by * 64, bcol = ct * 128;
    const int nt = 16;                         // K = 512

    const int sbr = w * 32 + (l >> 2);
    const int seg = (l & 3) * 8;

    const __bf16* Bg0 = BT + (size_t)(bcol + sbr) * 512 + seg;
    const __bf16* Bg1 = Bg0 + (size_t)16 * 512;

    f32x4 acc[2][4] = {};
    const int fr = l & 15, fk = (l >> 4) * 8;
    const int wr = (w >> 1) * 32, wc = (w & 1) * 64;
    const int kmax = (nt - 1) * 32;

    auto As = (__bf16 (*)[64][32])lds;
    auto Bs = (__bf16 (*)[128][32])(lds + 16384);

    const int sar = w * 16 + (l >> 2);
    const __bf16* Ar = A + (size_t)(brow + sar) * 512 + seg;

#define ISSUE_G8(slot)                                                        \
    {                                                                         \
        const int _s = (slot);                                                \
        const int _k = (_s * 32 < kmax) ? _s * 32 : kmax;                     \
        const int _b = _s & 3;                                                \
        gload16(Ar + _k,  &As[_b][w * 16][0]);                                \
        gload16(Bg0 + _k, &Bs[_b][w * 32][0]);                                \
        gload16(Bg1 + _k, &Bs[_b][w * 32 + 16][0]);                           \
    }

    ISSUE_G8(0) ISSUE_G8(1) ISSUE_G8(2)

    for (int t = 0; t < nt; ++t) {
        asm volatile("s_waitcnt vmcnt(6)" ::: "memory");
        asm volatile("s_waitcnt lgkmcnt(0)" ::: "memory");
        __builtin_amdgcn_s_barrier();

        const int bi = t & 3;
        bf16x8 a[2], b[4];
#pragma unroll
        for (int m = 0; m < 2; ++m) a[m] = *(const bf16x8*)&As[bi][wr + m * 16 + fr][fk];
#pragma unroll
        for (int n = 0; n < 4; ++n) b[n] = *(const bf16x8*)&Bs[bi][wc + n * 16 + fr][fk];

        ISSUE_G8(t + 3)

#pragma unroll
        for (int m = 0; m < 2; ++m)
#pragma unroll
            for (int n = 0; n < 4; ++n)
                acc[m][n] = __builtin_amdgcn_mfma_f32_16x16x32_bf16(a[m], b[n], acc[m][n], 0, 0, 0);
    }
#undef ISSUE_G8

    // fused GRU final epilogue
    const int fq = (l >> 4) * 4;
#pragma unroll
    for (int m = 0; m < 2; ++m)
#pragma unroll
        for (int n = 0; n < 4; ++n)
#pragma unroll
            for (int r = 0; r < 4; ++r) {
                int row = brow + wr + m * 16 + fq + r;
                int col = bcol + wc + n * 16 + fr;
                float xz = mx[(size_t)row * 1536 + col]        + bias[col];
                float xh = mx[(size_t)row * 1536 + 1024 + col] + bias[1024 + col];
                float mz = mi2[(size_t)row * 1024 + col];
                float hp = hprev[(size_t)row * 512 + col];
                float z  = 1.f / (1.f + expf(-(xz + mz)));
                float hh = tanhf(xh + acc[m][n][r]);
                h[(size_t)row * 512 + col] = z * hp + (1.f - z) * hh;
            }
}

// ---------------- prep: LDS-tiled weight transposes --------------------------
__global__ __launch_bounds__(256) void prep_wT(
    const float* __restrict__ ew1, const float* __restrict__ ew2,
    const float* __restrict__ w12, const float* __restrict__ u12,
    const float* __restrict__ v12, const float* __restrict__ w21,
    const float* __restrict__ u21, const float* __restrict__ v21,
    const float* __restrict__ cd_w, const float* __restrict__ cw_w,
    const float* __restrict__ kern, const float* __restrict__ rkern,
    __bf16* __restrict__ WT, __bf16* __restrict__ WcatT,
    __bf16* __restrict__ cdT, __bf16* __restrict__ cwT,
    __bf16* __restrict__ kernT, __bf16* __restrict__ rkernT)
{
    __shared__ float tile[64][65];
    const int b = blockIdx.x, tid = threadIdx.x;
    const int tr = tid >> 6, tc = tid & 63;

    const float* src = nullptr;
    int ldsrc = 0, srow0 = 0, scol0 = 0, kvalid = 1 << 30;
    __bf16* dst; int ldd, n0, k0;
    bool zero = false;

    if (b < 256) {                         // WT: out 512 x 2048
        int q = b; n0 = (q >> 5) * 64; k0 = (q & 31) * 64;
        dst = WT; ldd = 2048; kvalid = 2000; ldsrc = 256; srow0 = k0;
        if (n0 < 256) { src = ew1; scol0 = n0; } else { src = ew2; scol0 = n0 - 256; }
    } else if (b < 384) {                  // WcatT: out 1024 x 512
        int q = b - 256; n0 = (q >> 3) * 64; k0 = (q & 7) * 64;
        dst = WcatT; ldd = 512; ldsrc = 256; srow0 = k0 & 255; scol0 = n0 & 255;
        int qn = n0 >> 8; bool khi = k0 >= 256;
        if (qn == 0)      src = khi ? u12 : w12;
        else if (qn == 1) src = khi ? w21 : u21;
        else if (qn == 2) { if (khi) src = v12; else zero = true; }
        else              { if (khi) zero = true; else src = v21; }
    } else if (b < 448) {                  // cdT
        int q = b - 384; n0 = (q >> 3) * 64; k0 = (q & 7) * 64;
        src = cd_w; ldsrc = 512; srow0 = k0; scol0 = n0; dst = cdT; ldd = 512;
    } else if (b < 512) {                  // cwT
        int q = b - 448; n0 = (q >> 3) * 64; k0 = (q & 7) * 64;
        src = cw_w; ldsrc = 512; srow0 = k0; scol0 = n0; dst = cwT; ldd = 512;
    } else if (b < 704) {                  // kernT
        int q = b - 512; n0 = (q >> 3) * 64; k0 = (q & 7) * 64;
        src = kern; ldsrc = 1536; srow0 = k0; scol0 = n0; dst = kernT; ldd = 512;
    } else {                               // rkernT
        int q = b - 704; n0 = (q >> 3) * 64; k0 = (q & 7) * 64;
        src = rkern; ldsrc = 1536; srow0 = k0; scol0 = n0; dst = rkernT; ldd = 512;
    }

#pragma unroll
    for (int p = 0; p < 16; ++p) {
        int kr = p * 4 + tr;
        float v = 0.f;
        if (!zero && (srow0 + kr) < kvalid)
            v = src[(size_t)(srow0 + kr) * ldsrc + scol0 + tc];
        tile[kr][tc] = v;
    }
    __syncthreads();
#pragma unroll
    for (int p = 0; p < 16; ++p) {
        int nr = p * 4 + tr;
        dst[(size_t)(n0 + nr) * ldd + k0 + tc] = (__bf16)tile[tc][nr];
    }
}

// ---------------- R-A: E = bf16(sum2 P12), cro = bf16(tanh(P4 + cd_b)) ------
__global__ __launch_bounds__(256) void reduce_A(
    const float* __restrict__ P12, const float* __restrict__ P4,
    const float* __restrict__ cd_b,
    __bf16* __restrict__ E, __bf16* __restrict__ cro)
{
    const int S = 1 << 21;
    int b = blockIdx.x;
    int i = (((b & 2047) * 256) + threadIdx.x) * 4;
    if (b < 2048) {
        f32x4 p0 = *(const f32x4*)(P12 + i);
        f32x4 p1 = *(const f32x4*)(P12 + S + i);
        __bf16 o[4];
#pragma unroll
        for (int j = 0; j < 4; ++j) o[j] = (__bf16)(p0[j] + p1[j]);
        *(bf16x4*)&E[i] = *(bf16x4*)o;
    } else {
        f32x4 p0 = *(const f32x4*)(P4 + i);
        int c = i & 511;
        __bf16 o[4];
#pragma unroll
        for (int j = 0; j < 4; ++j) o[j] = (__bf16)tanhf(p0[j] + cd_b[c + j]);
        *(bf16x4*)&cro[i] = *(bf16x4*)o;
    }
}

// ---------------- fuse1: attention + x + crohis_new, and hprev ---------------
__global__ __launch_bounds__(256) void fuse1(
    const __bf16* __restrict__ T, const __bf16* __restrict__ E,
    const float* __restrict__ crohis,
    const float* __restrict__ P5,
    const float* __restrict__ h_tm1, const float* __restrict__ cw_b,
    __bf16* __restrict__ x, float* __restrict__ cro_out,
    float* __restrict__ hprev, __bf16* __restrict__ hprev_bf)
{
    __shared__ float s4[4];
    int b = blockIdx.x;
    int j = threadIdx.x;
    if (b < 4096) {
        const __bf16* t = T + (size_t)b * 1024;
        float s12 = tanhf((float)t[j])       * (float)t[512 + j];
        float s21 = tanhf((float)t[256 + j]) * (float)t[768 + j];
        float v = s12;
#pragma unroll
        for (int o = 32; o >= 1; o >>= 1) v = fmaxf(v, __shfl_xor(v, o, 64));
        __syncthreads(); if ((j & 63) == 0) s4[j >> 6] = v; __syncthreads();
        float m12 = fmaxf(fmaxf(s4[0], s4[1]), fmaxf(s4[2], s4[3]));
        float e12 = expf(s12 - m12);
        v = e12;
#pragma unroll
        for (int o = 32; o >= 1; o >>= 1) v += __shfl_xor(v, o, 64);
        __syncthreads(); if ((j & 63) == 0) s4[j >> 6] = v; __syncthreads();
        float sum12 = s4[0] + s4[1] + s4[2] + s4[3];
        v = s21;
#pragma unroll
        for (int o = 32; o >= 1; o >>= 1) v = fmaxf(v, __shfl_xor(v, o, 64));
        __syncthreads(); if ((j & 63) == 0) s4[j >> 6] = v; __syncthreads();
        float m21 = fmaxf(fmaxf(s4[0], s4[1]), fmaxf(s4[2], s4[3]));
        float e21 = expf(s21 - m21);
        v = e21;
#pragma unroll
        for (int o = 32; o >= 1; o >>= 1) v += __shfl_xor(v, o, 64);
        __syncthreads(); if ((j & 63) == 0) s4[j >> 6] = v; __syncthreads();
        float sum21 = s4[0] + s4[1] + s4[2] + s4[3];

        size_t b0 = (size_t)b * 512 + j, b1 = b0 + 256;
        float x1 = (float)E[b0] * (e12 / sum12);
        float x2 = (float)E[b1] * (e21 / sum21);
        x[b0] = (__bf16)x1;
        x[b1] = (__bf16)x2;
        cro_out[b0] = TAU_F * crohis[b0] + (1.f - TAU_F) * x1;
        cro_out[b1] = TAU_F * crohis[b1] + (1.f - TAU_F) * x2;
    } else {
        int i = ((b - 4096) * 256 + j) * 4;
        f32x4 p = *(const f32x4*)(P5 + i);
        f32x4 ht = *(const f32x4*)(h_tm1 + i);
        int c = i & 511;
        f32x4 o; __bf16 ob[4];
#pragma unroll
        for (int q = 0; q < 4; ++q) {
            float hv = ht[q] + tanhf(p[q] + cw_b[c + q]);
            o[q] = hv; ob[q] = (__bf16)hv;
        }
        *(f32x4*)(hprev + i) = o;
        *(bf16x4*)&hprev_bf[i] = *(bf16x4*)ob;
    }
}

// ---------------- gates: rh = sigmoid(mx_r + bias_r + mi_r) * hprev ----------
__global__ __launch_bounds__(256) void gates_k(
    const float* __restrict__ mx, const float* __restrict__ mi2,
    const float* __restrict__ hprev, const float* __restrict__ bias,
    __bf16* __restrict__ rh)
{
    int i = (blockIdx.x * 256 + threadIdx.x) * 4;
    int row = i >> 9, c = i & 511;
    f32x4 a  = *(const f32x4*)(mx + (size_t)row * 1536 + 512 + c);
    f32x4 m  = *(const f32x4*)(mi2 + (size_t)row * 1024 + 512 + c);
    f32x4 hp = *(const f32x4*)(hprev + i);
    f32x4 bb = *(const f32x4*)(bias + 512 + c);
    __bf16 o[4];
#pragma unroll
    for (int q = 0; q < 4; ++q) {
        float r = 1.f / (1.f + expf(-(a[q] + bb[q] + m[q])));
        o[q] = (__bf16)(r * hp[q]);
    }
    *(bf16x4*)&rh[i] = *(bf16x4*)o;
}

// ---------------- launch -----------------------------------------------------
extern "C" void kernel_launch(void* const* d_in, const int* in_sizes, int n_in,
                              void* d_out, int out_size, void* d_ws, size_t ws_size,
                              hipStream_t stream)
{
    (void)in_sizes; (void)n_in; (void)out_size; (void)ws_size;

    const float* inputs = (const float*)d_in[0];
    const float* h_tm1  = (const float*)d_in[1];
    const float* crohis = (const float*)d_in[2];
    const float* ew1    = (const float*)d_in[3];
    const float* ew2    = (const float*)d_in[4];
    const float* ca12w  = (const float*)d_in[5];
    const float* ca12u  = (const float*)d_in[6];
    const float* ca12v  = (const float*)d_in[7];
    const float* ca21w  = (const float*)d_in[8];
    const float* ca21u  = (const float*)d_in[9];
    const float* ca21v  = (const float*)d_in[10];
    const float* cw_w   = (const float*)d_in[11];
    const float* cw_b   = (const float*)d_in[12];
    const float* cd_w   = (const float*)d_in[13];
    const float* cd_b   = (const float*)d_in[14];
    const float* kern   = (const float*)d_in[15];
    const float* rkern  = (const float*)d_in[16];
    const float* bias   = (const float*)d_in[17];

    char* ws = (char*)d_ws;
    const size_t MB = 1 << 20;
    // layout identical to rev 10 (P8 slot now unused):
    float*  P12      = (float*)(ws + 0);
    float*  P4       = (float*)(ws + 16 * MB);
    __bf16* T        = (__bf16*)(ws + 16 * MB);
    float*  P5       = (float*)(ws + 32 * MB);
    __bf16* x        = (__bf16*)(ws + 40 * MB);
    __bf16* rh       = (__bf16*)(ws + 40 * MB);
    __bf16* E        = (__bf16*)(ws + 48 * MB);
    __bf16* cro_bf   = (__bf16*)(ws + 52 * MB);
    float*  hprev    = (float*)(ws + 60 * MB);
    __bf16* hprev_bf = (__bf16*)(ws + 68 * MB);
    float*  mx       = (float*)(ws + 0);
    float*  mi2      = (float*)(ws + 24 * MB);
    __bf16* WT       = (__bf16*)(ws + 72 * MB);               // 2MB
    __bf16* WcatT    = (__bf16*)(ws + 74 * MB);               // 1MB
    __bf16* cdT      = (__bf16*)(ws + 75 * MB);               // 0.5MB
    __bf16* cwT      = (__bf16*)(ws + 75 * MB + 512 * 1024);  // 0.5MB
    __bf16* kernT    = (__bf16*)(ws + 76 * MB);               // 1.5MB
    __bf16* rkernT   = (__bf16*)(ws + 77 * MB + 512 * 1024);  // ends 79MB

    float* h_out   = (float*)d_out;
    float* cro_out = (float*)d_out + 2 * 1048576;

    const int BIG = 1 << 30;
    const long long S2 = 1ll << 21;   // 8 MB in fp32 elems

    prep_wT<<<896, 256, 0, stream>>>(ew1, ew2, ca12w, ca12u, ca12v, ca21w,
                                     ca21u, ca21v, cd_w, cw_w, kern, rkern,
                                     WT, WcatT, cdT, cwT, kernT, rkernT);

    // Phase A (AFP32): G12 split-2 (fp32 inputs) + G4 (fp32 crohis)  [nwg=768]
    SubGemm gA1 = { inputs, 4000, 2000, WT,  2048, P12, 512, S2, 1024, 4, 2, 2000, 0 };
    SubGemm gA2 = { crohis,  512,  512, cdT,  512, P4,  512, 0,   512, 4, BIG, 0, 0 };
    gemm_dual<true><<<dim3(12, 64), 256, 0, stream>>>(gA1, gA2, 8);

    reduce_A<<<4096, 256, 0, stream>>>(P12, P4, cd_b, E, cro_bf);

    // Phase B: G3 (bf16 T out) + G5                                   [nwg=768]
    SubGemm gB1 = { E,      512, 512, WcatT, 512, (float*)T, 1024, 0, 512, 8, BIG, 0, 1 };
    SubGemm gB2 = { cro_bf, 512, 512, cwT,   512, P5,        512,  0, 512, 4, BIG, 0, 0 };
    gemm_dual<false><<<dim3(12, 64), 256, 0, stream>>>(gB1, gB2, 8);

    fuse1<<<6144, 256, 0, stream>>>(T, E, crohis, P5, h_tm1, cw_b,
                                    x, cro_out, hprev, hprev_bf);

    // Phase C: G6 (mx) + G7 (mi2)                                     [nwg=1280]
    SubGemm gC1 = { x,        512, 512, kernT,  512, mx,  1536, 0, 512, 12, BIG, 0, 0 };
    SubGemm gC2 = { hprev_bf, 512, 512, rkernT, 512, mi2, 1024, 0, 512, 8,  BIG, 0, 0 };
    gemm_dual<false><<<dim3(20, 64), 256, 0, stream>>>(gC1, gC2, 12);

    gates_k<<<2048, 256, 0, stream>>>(mx, mi2, hprev, bias, rh);

    // G8 + fused GRU final -> h                                        [nwg=256]
    gemm_g8<<<dim3(4, 64), 256, 0, stream>>>(
        rh, rkernT + (size_t)1024 * 512, mx, mi2, hprev, bias, h_out);
}